// Round 2
// baseline (44593.942 us; speedup 1.0000x reference)
//
#include <hip/hip_runtime.h>
#include <cstdint>
#include <cstddef>

#define NN 100000
#define NE 800000
#define NG 64
#define NT 4
#define DD 150
#define HIDN 512
#define NPASS 5
#define NBINS (NN*NT)
#define KP 160      // K padded to 160 (zeros) -> clean 8 chunks of 20, all b128
#define KC 20       // k-chunk staged in LDS
#define NCH (KP/KC) // 8 chunks
#define LDA 161     // LDS A-tile row stride: 4*LDA mod 32 = 4 -> 2-way (free)
#define RPB 16      // readout partial blocks per graph

static __device__ __forceinline__ float sigmoidf_(float x){ return 1.f/(1.f+expf(-x)); }

// ---------------- setup: counting sort of edges by (dst,type) ----------------

__global__ void count_kernel(const int* __restrict__ dst, const int* __restrict__ typ,
                             unsigned* __restrict__ deg){
  int e = blockIdx.x*256 + threadIdx.x;
  if (e < NE) atomicAdd(&deg[dst[e]*NT + typ[e]], 1u);
}

__device__ unsigned block_excl_base(unsigned threadSum){
  const int tid = threadIdx.x;
  const int lane = tid & 63, wid = tid >> 6;
  unsigned s = threadSum;
  #pragma unroll
  for (int d = 1; d < 64; d <<= 1){ unsigned t = __shfl_up(s, d); if (lane >= d) s += t; }
  __shared__ unsigned wsum[4];
  if (lane == 63) wsum[wid] = s;
  __syncthreads();
  unsigned base = 0;
  for (int w = 0; w < wid; w++) base += wsum[w];
  return base + s - threadSum;
}

__global__ void scan_reduce(const unsigned* __restrict__ deg, unsigned* __restrict__ bsum){
  const int base = blockIdx.x*1024 + threadIdx.x*4;
  unsigned s = 0;
  #pragma unroll
  for (int i = 0; i < 4; i++){ const int idx = base+i; if (idx < NBINS) s += deg[idx]; }
  #pragma unroll
  for (int d = 1; d < 64; d <<= 1) s += __shfl_down(s, d);
  __shared__ unsigned ws4[4];
  const int lane = threadIdx.x & 63, wid = threadIdx.x >> 6;
  if (lane == 0) ws4[wid] = s;
  __syncthreads();
  if (threadIdx.x == 0) bsum[blockIdx.x] = ws4[0]+ws4[1]+ws4[2]+ws4[3];
}

__global__ void scan_block(unsigned* bsum, int n){
  const int tid = threadIdx.x;
  unsigned v[4]; unsigned s = 0;
  #pragma unroll
  for (int i = 0; i < 4; i++){ const int idx = tid*4+i; v[i] = (idx < n) ? bsum[idx] : 0u; s += v[i]; }
  unsigned run = block_excl_base(s);
  #pragma unroll
  for (int i = 0; i < 4; i++){ const int idx = tid*4+i; if (idx < n) bsum[idx] = run; run += v[i]; }
}

__global__ void scan_final(const unsigned* __restrict__ deg, const unsigned* __restrict__ bsum,
                           unsigned* __restrict__ off){
  const int tid = threadIdx.x;
  const int base0 = blockIdx.x*1024 + tid*4;
  unsigned v[4]; unsigned s = 0;
  #pragma unroll
  for (int i = 0; i < 4; i++){ const int idx = base0+i; v[i] = (idx < NBINS) ? deg[idx] : 0u; s += v[i]; }
  unsigned run = block_excl_base(s) + bsum[blockIdx.x];
  #pragma unroll
  for (int i = 0; i < 4; i++){ const int idx = base0+i; if (idx < NBINS) off[idx] = run; run += v[i]; }
  if (blockIdx.x == 0 && tid == 0) off[NBINS] = NE;
}

__global__ void scatter_sort(const int* __restrict__ src, const int* __restrict__ dst,
                             const int* __restrict__ typ, unsigned* __restrict__ cur,
                             int* __restrict__ srcSorted){
  int e = blockIdx.x*256 + threadIdx.x;
  if (e < NE){
    const int bin = dst[e]*NT + typ[e];
    const unsigned p = atomicAdd(&cur[bin], 1u);
    srcSorted[p] = src[e];
  }
}

// pad W [rows][150] -> [rows][KP], zero-filled k>=150
__global__ void padW(const float* __restrict__ W, float* __restrict__ Wp, int rows){
  int idx = blockIdx.x*256 + threadIdx.x;
  if (idx < rows*KP){ const int n = idx/KP, k = idx - n*KP;
    Wp[idx] = (k < DD) ? W[n*DD + k] : 0.f; }
}

// ---------------- shared inner loop: 64x150 tile, thread-tile 4x10 ----------------
// As[64][LDA] row-major fp32 (cols 150..159 zeroed); Ws[150][KC] per chunk.

#define GEMM_ACC_DECL \
  const int tm = tid & 15, tn = tid >> 4; \
  float acc[4][10];

#define GEMM_CHUNK_COMPUTE(Asr, Wsr, k0) \
  { const float* Ab = &Asr[(4*tm)*LDA + (k0)]; \
    _Pragma("unroll") \
    for (int k4 = 0; k4 < KC/4; k4++){ \
      const int kk = 4*k4; \
      float a[4][4]; \
      _Pragma("unroll") \
      for (int r = 0; r < 4; r++){ \
        a[r][0]=Ab[r*LDA+kk]; a[r][1]=Ab[r*LDA+kk+1]; \
        a[r][2]=Ab[r*LDA+kk+2]; a[r][3]=Ab[r*LDA+kk+3]; } \
      _Pragma("unroll") \
      for (int j = 0; j < 10; j++){ \
        const int n = 16*j + tn; \
        if (n < DD){ \
          const float4 w = *(const float4*)(&Wsr[n*KC + kk]); \
          _Pragma("unroll") \
          for (int r = 0; r < 4; r++) \
            acc[r][j] = fmaf(a[r][0], w.x, fmaf(a[r][1], w.y, \
                        fmaf(a[r][2], w.z, fmaf(a[r][3], w.w, acc[r][j])))); } } } }

// ---------------- fused message kernel: inc = deg@b_e + sum_t agg_t @ W_t.T --------
__global__ __launch_bounds__(256, 3) void gemm_msg(
    const float* __restrict__ h, const int* __restrict__ srcSorted,
    const unsigned* __restrict__ off, const unsigned* __restrict__ deg,
    const float* __restrict__ b_e, const float* __restrict__ WpE,
    float* __restrict__ inc)
{
  __shared__ float As[64*LDA];
  __shared__ float Ws[DD*KC];
  const int tid = threadIdx.x;
  const int rowTile = blockIdx.x * 64;

  GEMM_ACC_DECL
  // bias init: acc[r][j] = sum_t deg[node,t] * b_e[t][col]
  #pragma unroll
  for (int r = 0; r < 4; r++){
    const int node = rowTile + 4*tm + r;
    float d0=0.f,d1=0.f,d2=0.f,d3=0.f;
    if (node < NN){
      const uint4 dg = *(const uint4*)(&deg[node*NT]);
      d0=(float)dg.x; d1=(float)dg.y; d2=(float)dg.z; d3=(float)dg.w;
    }
    #pragma unroll
    for (int j = 0; j < 10; j++){
      const int n = 16*j + tn;
      acc[r][j] = (n < DD)
        ? fmaf(d0, b_e[n], fmaf(d1, b_e[DD+n], fmaf(d2, b_e[2*DD+n], d3*b_e[3*DD+n])))
        : 0.f;
    }
  }

  for (int t = 0; t < NT; t++){
    __syncthreads();                       // protect As from previous type's readers
    { // gather-stage agg_t tile (full K row per node, zero pad 150..159)
      const int lane = tid & 63, sub = tid >> 6;
      for (int i = 0; i < 16; i++){
        const int m = sub*16 + i;
        const int node = rowTile + m;
        float a0 = 0.f, a1 = 0.f, a2 = 0.f;
        if (node < NN){
          const int bin = node*NT + t;
          const unsigned lo = off[bin], hi = off[bin+1];
          for (unsigned e = lo; e < hi; e++){
            const int s = srcSorted[e];
            const float* hp = h + (size_t)s*DD;
            a0 += hp[lane];
            a1 += hp[lane+64];
            if (lane < DD-128) a2 += hp[lane+128];
          }
        }
        As[m*LDA + lane]      = a0;
        As[m*LDA + 64 + lane] = a1;
        if (lane < 32) As[m*LDA + 128 + lane] = (lane < DD-128) ? a2 : 0.f;
      }
    }
    const float* Wt = WpE + (size_t)t*DD*KP;
    for (int c = 0; c < NCH; c++){
      __syncthreads();
      for (int i = tid; i < DD*KC; i += 256){
        const int n = i/KC, kk = i - n*KC;
        Ws[i] = Wt[n*KP + c*KC + kk];
      }
      __syncthreads();
      GEMM_CHUNK_COMPUTE(As, Ws, c*KC)
    }
  }

  #pragma unroll
  for (int r = 0; r < 4; r++){
    const int row = rowTile + 4*tm + r;
    if (row < NN){
      #pragma unroll
      for (int j = 0; j < 10; j++){
        const int n = 16*j + tn;
        if (n < DD) inc[(size_t)row*DD + n] = acc[r][j];
      }
    }
  }
}

// ---------------- plain gemm: C[row, col0+n] = A[row,:]@W[col0+n,:] + bias --------
__global__ __launch_bounds__(256, 3) void gemm_lin(
    const float* __restrict__ A, const float* __restrict__ Wp,
    float* __restrict__ C, const float* __restrict__ bias, int M, int ldc)
{
  __shared__ float As[64*LDA];
  __shared__ float Ws[DD*KC];
  const int tid = threadIdx.x;
  const int rowTile = blockIdx.x * 64;
  const float* __restrict__ Wt = Wp + (size_t)blockIdx.y * (DD*KP);
  const int col0 = blockIdx.y * DD;

  // stage A tile: float2 global loads (rows are 600B stride -> 8B aligned)
  for (int i2 = tid; i2 < 64*(KP/2); i2 += 256){
    const int m = i2 / (KP/2), kk2 = i2 - m*(KP/2);
    const int k = 2*kk2;
    const int row = rowTile + m;
    float x = 0.f, y = 0.f;
    if (row < M && k < DD){
      const float2 v = *(const float2*)(A + (size_t)row*DD + k);
      x = v.x; y = v.y;
    }
    As[m*LDA + k]   = x;
    As[m*LDA + k+1] = y;
  }

  GEMM_ACC_DECL
  #pragma unroll
  for (int r = 0; r < 4; r++)
    #pragma unroll
    for (int j = 0; j < 10; j++) acc[r][j] = 0.f;

  for (int c = 0; c < NCH; c++){
    __syncthreads();
    for (int i = tid; i < DD*KC; i += 256){
      const int n = i/KC, kk = i - n*KC;
      Ws[i] = Wt[n*KP + c*KC + kk];
    }
    __syncthreads();
    GEMM_CHUNK_COMPUTE(As, Ws, c*KC)
  }

  #pragma unroll
  for (int r = 0; r < 4; r++){
    const int row = rowTile + 4*tm + r;
    if (row < M){
      #pragma unroll
      for (int j = 0; j < 10; j++){
        const int n = 16*j + tn;
        if (n < DD) C[(size_t)row*ldc + col0 + n] = acc[r][j] + bias[col0 + n];
      }
    }
  }
}

// ---------------- GRU elementwise (float2; gate order r,z,n) ----------------
__global__ void gru_kernel(const float* __restrict__ GI, const float* __restrict__ GH,
                           float* __restrict__ h, int c0, int m){
  const int idx = blockIdx.x*256 + threadIdx.x;
  if (idx >= m*(DD/2)) return;
  const int i = idx / (DD/2), d = (idx - i*(DD/2))*2;
  const float* gi = GI + (size_t)i*3*DD;
  const float* gh = GH + (size_t)i*3*DD;
  const float2 ir = *(const float2*)(gi + d);
  const float2 iz = *(const float2*)(gi + DD + d);
  const float2 in = *(const float2*)(gi + 2*DD + d);
  const float2 hr = *(const float2*)(gh + d);
  const float2 hz = *(const float2*)(gh + DD + d);
  const float2 hn = *(const float2*)(gh + 2*DD + d);
  float* hp = h + (size_t)(c0+i)*DD + d;
  const float2 hv = *(const float2*)hp;
  float2 o;
  { const float r = sigmoidf_(ir.x + hr.x), z = sigmoidf_(iz.x + hz.x);
    const float n = tanhf(in.x + r*hn.x); o.x = (1.f - z)*n + z*hv.x; }
  { const float r = sigmoidf_(ir.y + hr.y), z = sigmoidf_(iz.y + hz.y);
    const float n = tanhf(in.y + r*hn.y); o.y = (1.f - z)*n + z*hv.y; }
  *(float2*)hp = o;
}

// ---------------- readout: two-stage segment sum, log/nan/relu, concat ----------------
__global__ void readout1(const float* __restrict__ h, const int* __restrict__ gids,
                         float* __restrict__ part){
  const int g = blockIdx.x >> 4, s = blockIdx.x & (RPB-1);
  const int tid = threadIdx.x;
  __shared__ int sb[2];
  if (tid < 2){
    const int target = g + tid;
    int lo = 0, hi = NN;
    while (lo < hi){ const int mid = (lo+hi) >> 1; if (gids[mid] < target) lo = mid+1; else hi = mid; }
    sb[tid] = lo;
  }
  __syncthreads();
  const int lo = sb[0], hi = sb[1];
  const int len = hi - lo;
  const int per = (len + RPB - 1) / RPB;
  const int nlo = lo + s*per;
  const int nhi = (nlo + per < hi) ? (nlo + per) : hi;
  if (tid < DD){
    float acc = 0.f;
    for (int n = nlo; n < nhi; n++) acc += h[(size_t)n*DD + tid];
    part[(size_t)blockIdx.x*DD + tid] = acc;
  }
}

__global__ void readout2(const float* __restrict__ part, const float* __restrict__ pclass,
                         float* __restrict__ xbuf){
  const int g = blockIdx.x, tid = threadIdx.x;
  if (tid < DD){
    float acc = 0.f;
    #pragma unroll
    for (int s = 0; s < RPB; s++) acc += part[(size_t)(g*RPB + s)*DD + tid];
    float l = logf(acc);            // log(neg)=NaN, log(0)=-inf
    if (isnan(l)) l = 0.f;          // nan -> 0
    l = fmaxf(l, 0.f);              // relu (also kills -inf)
    xbuf[g*(DD+1)+tid] = l;
  }
  if (tid == DD) xbuf[g*(DD+1)+DD] = pclass[g];
}

__global__ void fc1_kernel(const float* __restrict__ xbuf, const float* __restrict__ w,
                           const float* __restrict__ b, float* __restrict__ hid){
  const int g = blockIdx.x, tid = threadIdx.x;   // 512 threads
  __shared__ float xs[DD+1];
  if (tid < DD+1) xs[tid] = xbuf[g*(DD+1)+tid];
  __syncthreads();
  float acc = b[tid];
  for (int k = 0; k < DD+1; k++) acc = fmaf(xs[k], w[k*HIDN + tid], acc);
  hid[g*HIDN + tid] = (acc > 0.f) ? acc : 0.01f*acc;   // leaky_relu(0.01)
}

__global__ void fc2_kernel(const float* __restrict__ hid, const float* __restrict__ w,
                           const float* __restrict__ b, float* __restrict__ out){
  const int g = blockIdx.x, tid = threadIdx.x;   // 64 threads
  __shared__ float hs[HIDN];
  for (int i = tid; i < HIDN; i += 64) hs[i] = hid[g*HIDN + i];
  __syncthreads();
  if (tid < 10){
    float acc = b[tid];
    for (int k = 0; k < HIDN; k++) acc = fmaf(hs[k], w[k*10 + tid], acc);
    out[g*10 + tid] = acc;
  }
}

// ---------------- host orchestration ----------------
extern "C" void kernel_launch(void* const* d_in, const int* in_sizes, int n_in,
                              void* d_out, int out_size, void* d_ws, size_t ws_size,
                              hipStream_t stream)
{
  (void)in_sizes; (void)n_in; (void)out_size;
  const float* nodes  = (const float*)d_in[0];
  const float* pclass = (const float*)d_in[1];
  const int*   esrc   = (const int*)d_in[2];
  const int*   edst   = (const int*)d_in[3];
  const int*   etyp   = (const int*)d_in[4];
  const int*   gids   = (const int*)d_in[5];
  const float* W_e    = (const float*)d_in[6];
  const float* b_e    = (const float*)d_in[7];
  const float* w_ih   = (const float*)d_in[8];
  const float* w_hh   = (const float*)d_in[9];
  const float* b_ih   = (const float*)d_in[10];
  const float* b_hh   = (const float*)d_in[11];
  const float* fc1w   = (const float*)d_in[12];
  const float* fc1b   = (const float*)d_in[13];
  const float* fc2w   = (const float*)d_in[14];
  const float* fc2b   = (const float*)d_in[15];
  float* out = (float*)d_out;

  char* p = (char*)d_ws;
  auto alloc = [&](size_t bytes)->char* {
    char* r = p; p += ((bytes + 255) & ~(size_t)255); return r;
  };
  float*    h    = (float*)alloc((size_t)NN*DD*4);          // 60 MB
  float*    inc  = (float*)alloc((size_t)NN*DD*4);          // 60 MB
  unsigned* deg  = (unsigned*)alloc((size_t)NBINS*4);
  unsigned* off  = (unsigned*)alloc((size_t)(NBINS+1)*4);
  unsigned* cur  = (unsigned*)alloc((size_t)NBINS*4);
  unsigned* bsum = (unsigned*)alloc(4096);
  int*      srcS = (int*)alloc((size_t)NE*4);
  float*    WpE  = (float*)alloc((size_t)NT*DD*KP*4);
  float*    WpI  = (float*)alloc((size_t)3*DD*KP*4);
  float*    WpH  = (float*)alloc((size_t)3*DD*KP*4);
  float*    part = (float*)alloc((size_t)NG*RPB*DD*4);
  float*    xbuf = (float*)alloc((size_t)NG*(DD+1)*4);
  float*    hidb = (float*)alloc((size_t)NG*HIDN*4);

  const size_t used = (size_t)(p - (char*)d_ws);
  const size_t remain = (ws_size > used) ? (ws_size - used) : 0;
  long long cm = (long long)(remain / (2ull*3*DD*4));
  if (cm > NN) cm = NN;
  cm &= ~63LL;
  if (cm < 64) cm = 64;
  const int chunkM = (int)cm;
  float* GI = (float*)p;
  float* GH = GI + (size_t)chunkM*3*DD;

  // --- per-launch setup (edge CSR sort + padded weights + h init) ---
  hipMemsetAsync(deg, 0, (size_t)NBINS*4, stream);
  count_kernel<<<(NE+255)/256, 256, 0, stream>>>(edst, etyp, deg);
  const int SCB = (NBINS + 1023)/1024;   // 391
  scan_reduce<<<SCB, 256, 0, stream>>>(deg, bsum);
  scan_block<<<1, 256, 0, stream>>>(bsum, SCB);
  scan_final<<<SCB, 256, 0, stream>>>(deg, bsum, off);
  hipMemcpyAsync(cur, off, (size_t)NBINS*4, hipMemcpyDeviceToDevice, stream);
  scatter_sort<<<(NE+255)/256, 256, 0, stream>>>(esrc, edst, etyp, cur, srcS);
  padW<<<(NT*DD*KP+255)/256, 256, 0, stream>>>(W_e, WpE, NT*DD);
  padW<<<(3*DD*KP+255)/256, 256, 0, stream>>>(w_ih, WpI, 3*DD);
  padW<<<(3*DD*KP+255)/256, 256, 0, stream>>>(w_hh, WpH, 3*DD);
  hipMemcpyAsync(h, nodes, (size_t)NN*DD*4, hipMemcpyDeviceToDevice, stream);

  const int grows = (NN + 63)/64;
  for (int pass = 0; pass < NPASS; pass++) {
    gemm_msg<<<grows, 256, 0, stream>>>(h, srcS, off, deg, b_e, WpE, inc);
    for (int c = 0; c < NN; c += chunkM) {
      const int m = (NN - c < chunkM) ? (NN - c) : chunkM;
      const int gb = (m + 63)/64;
      gemm_lin<<<dim3(gb,3), 256, 0, stream>>>(inc + (size_t)c*DD, WpI, GI, b_ih, m, 3*DD);
      gemm_lin<<<dim3(gb,3), 256, 0, stream>>>(h   + (size_t)c*DD, WpH, GH, b_hh, m, 3*DD);
      gru_kernel<<<(int)(((size_t)m*(DD/2) + 255)/256), 256, 0, stream>>>(GI, GH, h, c, m);
    }
  }

  readout1<<<NG*RPB, 256, 0, stream>>>(h, gids, part);
  readout2<<<NG, 256, 0, stream>>>(part, pclass, xbuf);
  fc1_kernel<<<NG, HIDN, 0, stream>>>(xbuf, fc1w, fc1b, hidb);
  fc2_kernel<<<NG, 64, 0, stream>>>(hidb, fc2w, fc2b, out);
}

// Round 4
// 21892.767 us; speedup vs baseline: 2.0369x; 2.0369x over previous
//
#include <hip/hip_runtime.h>
#include <cstdint>
#include <cstddef>

#define NN 100000
#define NE 800000
#define NG 64
#define NT 4
#define DD 150
#define HIDN 512
#define NPASS 5
#define NBINS (NN*NT)
#define TM 32      // A-tile rows: LDS 32*151*4 = 19328 B -> 7 blocks/CU
#define LDA 151    // A-tile row stride
#define WPS 152    // padded W row stride (floats): rows 16B-aligned for float4 loads
#define RPB 16     // readout partial blocks per graph
#define CHUNK_CAP 25024  // GI+GH <= 2*25024*450*4 = 90 MB -> LLC-resident

static __device__ __forceinline__ float sigmoidf_(float x){ return 1.f/(1.f+expf(-x)); }

// ---------------- setup: counting sort of edges by (dst,type) ----------------

__global__ void count_kernel(const int* __restrict__ dst, const int* __restrict__ typ,
                             unsigned* __restrict__ deg){
  int e = blockIdx.x*256 + threadIdx.x;
  if (e < NE) atomicAdd(&deg[dst[e]*NT + typ[e]], 1u);
}

__device__ unsigned block_excl_base(unsigned threadSum){
  const int tid = threadIdx.x;
  const int lane = tid & 63, wid = tid >> 6;
  unsigned s = threadSum;
  #pragma unroll
  for (int d = 1; d < 64; d <<= 1){ unsigned t = __shfl_up(s, d); if (lane >= d) s += t; }
  __shared__ unsigned wsum[4];
  if (lane == 63) wsum[wid] = s;
  __syncthreads();
  unsigned base = 0;
  for (int w = 0; w < wid; w++) base += wsum[w];
  return base + s - threadSum;
}

__global__ void scan_reduce(const unsigned* __restrict__ deg, unsigned* __restrict__ bsum){
  const int base = blockIdx.x*1024 + threadIdx.x*4;
  unsigned s = 0;
  #pragma unroll
  for (int i = 0; i < 4; i++){ const int idx = base+i; if (idx < NBINS) s += deg[idx]; }
  #pragma unroll
  for (int d = 1; d < 64; d <<= 1) s += __shfl_down(s, d);
  __shared__ unsigned ws4[4];
  const int lane = threadIdx.x & 63, wid = threadIdx.x >> 6;
  if (lane == 0) ws4[wid] = s;
  __syncthreads();
  if (threadIdx.x == 0) bsum[blockIdx.x] = ws4[0]+ws4[1]+ws4[2]+ws4[3];
}

__global__ void scan_block(unsigned* bsum, int n){
  const int tid = threadIdx.x;
  unsigned v[4]; unsigned s = 0;
  #pragma unroll
  for (int i = 0; i < 4; i++){ const int idx = tid*4+i; v[i] = (idx < n) ? bsum[idx] : 0u; s += v[i]; }
  unsigned run = block_excl_base(s);
  #pragma unroll
  for (int i = 0; i < 4; i++){ const int idx = tid*4+i; if (idx < n) bsum[idx] = run; run += v[i]; }
}

__global__ void scan_final(const unsigned* __restrict__ deg, const unsigned* __restrict__ bsum,
                           unsigned* __restrict__ off){
  const int tid = threadIdx.x;
  const int base0 = blockIdx.x*1024 + tid*4;
  unsigned v[4]; unsigned s = 0;
  #pragma unroll
  for (int i = 0; i < 4; i++){ const int idx = base0+i; v[i] = (idx < NBINS) ? deg[idx] : 0u; s += v[i]; }
  unsigned run = block_excl_base(s) + bsum[blockIdx.x];
  #pragma unroll
  for (int i = 0; i < 4; i++){ const int idx = base0+i; if (idx < NBINS) off[idx] = run; run += v[i]; }
  if (blockIdx.x == 0 && tid == 0) off[NBINS] = NE;
}

__global__ void scatter_sort(const int* __restrict__ src, const int* __restrict__ dst,
                             const int* __restrict__ typ, unsigned* __restrict__ cur,
                             int* __restrict__ srcSorted){
  int e = blockIdx.x*256 + threadIdx.x;
  if (e < NE){
    const int bin = dst[e]*NT + typ[e];
    const unsigned p = atomicAdd(&cur[bin], 1u);
    srcSorted[p] = src[e];
  }
}

__global__ void padW(const float* __restrict__ W, float* __restrict__ Wp, int rows){
  int idx = blockIdx.x*256 + threadIdx.x;
  if (idx < rows*DD){ const int n = idx/DD, k = idx - n*DD; Wp[n*WPS + k] = W[idx]; }
}

// ---------------- GEMM core: 32-row A-tile in LDS, W streamed from global ----------------
// thread-tile: 2 rows (2*tm, 2*tm+1) x 10 cols (16*j + tn), 256 threads.

#define GEMM_COMPUTE_BODY(Ab, Wb) \
  _Pragma("unroll 2") \
  for (int k4 = 0; k4 < 37; k4++){ \
    const int k = 4*k4; \
    float a[2][4]; \
    _Pragma("unroll") \
    for (int r = 0; r < 2; r++){ \
      a[r][0]=Ab[r*LDA+k];   a[r][1]=Ab[r*LDA+k+1]; \
      a[r][2]=Ab[r*LDA+k+2]; a[r][3]=Ab[r*LDA+k+3]; } \
    _Pragma("unroll") \
    for (int j = 0; j < 10; j++){ \
      const int n = 16*j + tn; \
      if (n < DD){ \
        const float4 w = *(const float4*)(Wb + (size_t)n*WPS + k); \
        _Pragma("unroll") \
        for (int r = 0; r < 2; r++) \
          acc[r][j] = fmaf(a[r][0], w.x, fmaf(a[r][1], w.y, \
                      fmaf(a[r][2], w.z, fmaf(a[r][3], w.w, acc[r][j])))); } } } \
  { /* k tail: 148, 149 */ \
    float a[2][2]; \
    _Pragma("unroll") \
    for (int r = 0; r < 2; r++){ a[r][0]=Ab[r*LDA+148]; a[r][1]=Ab[r*LDA+149]; } \
    _Pragma("unroll") \
    for (int j = 0; j < 10; j++){ \
      const int n = 16*j + tn; \
      if (n < DD){ \
        const float2 w = *(const float2*)(Wb + (size_t)n*WPS + 148); \
        _Pragma("unroll") \
        for (int r = 0; r < 2; r++) \
          acc[r][j] = fmaf(a[r][0], w.x, fmaf(a[r][1], w.y, acc[r][j])); } } }

// message kernel (one edge type): INIT -> inc = deg@b_e + agg@W^T ; else inc += agg@W^T
template<bool INIT>
__global__ __launch_bounds__(256, 7) void gemm_msg(
    const float* __restrict__ h, const int* __restrict__ srcSorted,
    const unsigned* __restrict__ off, const unsigned* __restrict__ deg,
    const float* __restrict__ b_e, const float* __restrict__ Wb,
    float* __restrict__ inc, int typeT)
{
  __shared__ float As[TM*LDA];
  const int tid = threadIdx.x;
  const int rowTile = blockIdx.x * TM;

  { // gather-stage agg tile: 4 sub-waves x (TM/4) rows each  [bugfix: was TM/8]
    const int lane = tid & 63, sub = tid >> 6;
    #pragma unroll
    for (int i = 0; i < TM/4; i++){
      const int m = sub*(TM/4) + i;
      const int node = rowTile + m;
      float a0 = 0.f, a1 = 0.f, a2 = 0.f;
      if (node < NN){
        const int bin = node*NT + typeT;
        const unsigned lo = off[bin], hi = off[bin+1];
        for (unsigned e = lo; e < hi; e++){
          const int s = srcSorted[e];
          const float* hp = h + (size_t)s*DD;
          a0 += hp[lane];
          a1 += hp[lane+64];
          if (lane < DD-128) a2 += hp[lane+128];
        }
      }
      As[m*LDA + lane]      = a0;
      As[m*LDA + 64 + lane] = a1;
      if (lane < DD-128) As[m*LDA + 128 + lane] = a2;
    }
  }
  __syncthreads();

  const int tm = tid & 15, tn = tid >> 4;
  float acc[2][10];
  #pragma unroll
  for (int r = 0; r < 2; r++)
    #pragma unroll
    for (int j = 0; j < 10; j++) acc[r][j] = 0.f;

  const float* Ab = &As[(2*tm)*LDA];
  GEMM_COMPUTE_BODY(Ab, Wb)

  #pragma unroll
  for (int r = 0; r < 2; r++){
    const int row = rowTile + 2*tm + r;
    if (row < NN){
      float dbias[10];
      if (INIT){
        const uint4 dg = *(const uint4*)(&deg[row*NT]);
        const float d0=(float)dg.x, d1=(float)dg.y, d2=(float)dg.z, d3=(float)dg.w;
        #pragma unroll
        for (int j = 0; j < 10; j++){
          const int n = 16*j + tn;
          dbias[j] = (n < DD)
            ? fmaf(d0, b_e[n], fmaf(d1, b_e[DD+n], fmaf(d2, b_e[2*DD+n], d3*b_e[3*DD+n])))
            : 0.f;
        }
      }
      #pragma unroll
      for (int j = 0; j < 10; j++){
        const int n = 16*j + tn;
        if (n < DD){
          const size_t ci = (size_t)row*DD + n;
          if (INIT) inc[ci] = acc[r][j] + dbias[j];
          else      inc[ci] += acc[r][j];
        }
      }
    }
  }
}

// plain gemm: C[row, col0+n] = A[row,:]@W[col0+n,:] + bias
__global__ __launch_bounds__(256, 7) void gemm_lin(
    const float* __restrict__ A, const float* __restrict__ Wp,
    float* __restrict__ C, const float* __restrict__ bias, int M, int ldc)
{
  __shared__ float As[TM*LDA];
  const int tid = threadIdx.x;
  const int rowTile = blockIdx.x * TM;
  const float* __restrict__ Wb = Wp + (size_t)blockIdx.y * (DD*WPS);
  const int col0 = blockIdx.y * DD;

  // stage A tile: float2 loads (rows are 600 B stride -> 8 B aligned)
  for (int i2 = tid; i2 < TM*(DD/2); i2 += 256){
    const int m = i2 / (DD/2), kk2 = i2 - m*(DD/2);
    const int k = 2*kk2;
    const int row = rowTile + m;
    float2 v = make_float2(0.f, 0.f);
    if (row < M) v = *(const float2*)(A + (size_t)row*DD + k);
    As[m*LDA + k]   = v.x;
    As[m*LDA + k+1] = v.y;
  }
  __syncthreads();

  const int tm = tid & 15, tn = tid >> 4;
  float acc[2][10];
  #pragma unroll
  for (int r = 0; r < 2; r++)
    #pragma unroll
    for (int j = 0; j < 10; j++) acc[r][j] = 0.f;

  const float* Ab = &As[(2*tm)*LDA];
  GEMM_COMPUTE_BODY(Ab, Wb)

  #pragma unroll
  for (int r = 0; r < 2; r++){
    const int row = rowTile + 2*tm + r;
    if (row < M){
      #pragma unroll
      for (int j = 0; j < 10; j++){
        const int n = 16*j + tn;
        if (n < DD) C[(size_t)row*ldc + col0 + n] = acc[r][j] + bias[col0 + n];
      }
    }
  }
}

// ---------------- GRU elementwise (float2; gate order r,z,n) ----------------
__global__ void gru_kernel(const float* __restrict__ GI, const float* __restrict__ GH,
                           float* __restrict__ h, int c0, int m){
  const int idx = blockIdx.x*256 + threadIdx.x;
  if (idx >= m*(DD/2)) return;
  const int i = idx / (DD/2), d = (idx - i*(DD/2))*2;
  const float* gi = GI + (size_t)i*3*DD;
  const float* gh = GH + (size_t)i*3*DD;
  const float2 ir = *(const float2*)(gi + d);
  const float2 iz = *(const float2*)(gi + DD + d);
  const float2 in = *(const float2*)(gi + 2*DD + d);
  const float2 hr = *(const float2*)(gh + d);
  const float2 hz = *(const float2*)(gh + DD + d);
  const float2 hn = *(const float2*)(gh + 2*DD + d);
  float* hp = h + (size_t)(c0+i)*DD + d;
  const float2 hv = *(const float2*)hp;
  float2 o;
  { const float r = sigmoidf_(ir.x + hr.x), z = sigmoidf_(iz.x + hz.x);
    const float n = tanhf(in.x + r*hn.x); o.x = (1.f - z)*n + z*hv.x; }
  { const float r = sigmoidf_(ir.y + hr.y), z = sigmoidf_(iz.y + hz.y);
    const float n = tanhf(in.y + r*hn.y); o.y = (1.f - z)*n + z*hv.y; }
  *(float2*)hp = o;
}

// ---------------- readout: two-stage segment sum, log/nan/relu, concat ----------------
__global__ void readout1(const float* __restrict__ h, const int* __restrict__ gids,
                         float* __restrict__ part){
  const int g = blockIdx.x >> 4, s = blockIdx.x & (RPB-1);
  const int tid = threadIdx.x;
  __shared__ int sb[2];
  if (tid < 2){
    const int target = g + tid;
    int lo = 0, hi = NN;
    while (lo < hi){ const int mid = (lo+hi) >> 1; if (gids[mid] < target) lo = mid+1; else hi = mid; }
    sb[tid] = lo;
  }
  __syncthreads();
  const int lo = sb[0], hi = sb[1];
  const int len = hi - lo;
  const int per = (len + RPB - 1) / RPB;
  const int nlo = lo + s*per;
  const int nhi = (nlo + per < hi) ? (nlo + per) : hi;
  if (tid < DD){
    float acc = 0.f;
    for (int n = nlo; n < nhi; n++) acc += h[(size_t)n*DD + tid];
    part[(size_t)blockIdx.x*DD + tid] = acc;
  }
}

__global__ void readout2(const float* __restrict__ part, const float* __restrict__ pclass,
                         float* __restrict__ xbuf){
  const int g = blockIdx.x, tid = threadIdx.x;
  if (tid < DD){
    float acc = 0.f;
    #pragma unroll
    for (int s = 0; s < RPB; s++) acc += part[(size_t)(g*RPB + s)*DD + tid];
    float l = logf(acc);            // log(neg)=NaN, log(0)=-inf
    if (isnan(l)) l = 0.f;          // nan -> 0
    l = fmaxf(l, 0.f);              // relu (also kills -inf)
    xbuf[g*(DD+1)+tid] = l;
  }
  if (tid == DD) xbuf[g*(DD+1)+DD] = pclass[g];
}

__global__ void fc1_kernel(const float* __restrict__ xbuf, const float* __restrict__ w,
                           const float* __restrict__ b, float* __restrict__ hid){
  const int g = blockIdx.x, tid = threadIdx.x;   // 512 threads
  __shared__ float xs[DD+1];
  if (tid < DD+1) xs[tid] = xbuf[g*(DD+1)+tid];
  __syncthreads();
  float acc = b[tid];
  for (int k = 0; k < DD+1; k++) acc = fmaf(xs[k], w[k*HIDN + tid], acc);
  hid[g*HIDN + tid] = (acc > 0.f) ? acc : 0.01f*acc;   // leaky_relu(0.01)
}

__global__ void fc2_kernel(const float* __restrict__ hid, const float* __restrict__ w,
                           const float* __restrict__ b, float* __restrict__ out){
  const int g = blockIdx.x, tid = threadIdx.x;   // 64 threads
  __shared__ float hs[HIDN];
  for (int i = tid; i < HIDN; i += 64) hs[i] = hid[g*HIDN + i];
  __syncthreads();
  if (tid < 10){
    float acc = b[tid];
    for (int k = 0; k < HIDN; k++) acc = fmaf(hs[k], w[k*10 + tid], acc);
    out[g*10 + tid] = acc;
  }
}

// ---------------- host orchestration ----------------
extern "C" void kernel_launch(void* const* d_in, const int* in_sizes, int n_in,
                              void* d_out, int out_size, void* d_ws, size_t ws_size,
                              hipStream_t stream)
{
  (void)in_sizes; (void)n_in; (void)out_size;
  const float* nodes  = (const float*)d_in[0];
  const float* pclass = (const float*)d_in[1];
  const int*   esrc   = (const int*)d_in[2];
  const int*   edst   = (const int*)d_in[3];
  const int*   etyp   = (const int*)d_in[4];
  const int*   gids   = (const int*)d_in[5];
  const float* W_e    = (const float*)d_in[6];
  const float* b_e    = (const float*)d_in[7];
  const float* w_ih   = (const float*)d_in[8];
  const float* w_hh   = (const float*)d_in[9];
  const float* b_ih   = (const float*)d_in[10];
  const float* b_hh   = (const float*)d_in[11];
  const float* fc1w   = (const float*)d_in[12];
  const float* fc1b   = (const float*)d_in[13];
  const float* fc2w   = (const float*)d_in[14];
  const float* fc2b   = (const float*)d_in[15];
  float* out = (float*)d_out;

  char* p = (char*)d_ws;
  auto alloc = [&](size_t bytes)->char* {
    char* r = p; p += ((bytes + 255) & ~(size_t)255); return r;
  };
  float*    h    = (float*)alloc((size_t)NN*DD*4);          // 60 MB
  float*    inc  = (float*)alloc((size_t)NN*DD*4);          // 60 MB
  unsigned* deg  = (unsigned*)alloc((size_t)NBINS*4);
  unsigned* off  = (unsigned*)alloc((size_t)(NBINS+1)*4);
  unsigned* cur  = (unsigned*)alloc((size_t)NBINS*4);
  unsigned* bsum = (unsigned*)alloc(4096);
  int*      srcS = (int*)alloc((size_t)NE*4);
  float*    WpE  = (float*)alloc((size_t)NT*DD*WPS*4);
  float*    WpI  = (float*)alloc((size_t)3*DD*WPS*4);
  float*    WpH  = (float*)alloc((size_t)3*DD*WPS*4);
  float*    part = (float*)alloc((size_t)NG*RPB*DD*4);
  float*    xbuf = (float*)alloc((size_t)NG*(DD+1)*4);
  float*    hidb = (float*)alloc((size_t)NG*HIDN*4);

  const size_t used = (size_t)(p - (char*)d_ws);
  const size_t remain = (ws_size > used) ? (ws_size - used) : 0;
  long long cm = (long long)(remain / (2ull*3*DD*4));
  if (cm > CHUNK_CAP) cm = CHUNK_CAP;   // keep GI/GH LLC-resident (<= 90 MB)
  cm &= ~63LL;
  if (cm < 64) cm = 64;
  const int chunkM = (int)cm;
  float* GI = (float*)p;
  float* GH = GI + (size_t)chunkM*3*DD;

  // --- per-launch setup (edge CSR sort + padded weights + h init) ---
  hipMemsetAsync(deg, 0, (size_t)NBINS*4, stream);
  count_kernel<<<(NE+255)/256, 256, 0, stream>>>(edst, etyp, deg);
  const int SCB = (NBINS + 1023)/1024;   // 391
  scan_reduce<<<SCB, 256, 0, stream>>>(deg, bsum);
  scan_block<<<1, 256, 0, stream>>>(bsum, SCB);
  scan_final<<<SCB, 256, 0, stream>>>(deg, bsum, off);
  hipMemcpyAsync(cur, off, (size_t)NBINS*4, hipMemcpyDeviceToDevice, stream);
  scatter_sort<<<(NE+255)/256, 256, 0, stream>>>(esrc, edst, etyp, cur, srcS);
  padW<<<(NT*DD*DD+255)/256, 256, 0, stream>>>(W_e, WpE, NT*DD);
  padW<<<(3*DD*DD+255)/256, 256, 0, stream>>>(w_ih, WpI, 3*DD);
  padW<<<(3*DD*DD+255)/256, 256, 0, stream>>>(w_hh, WpH, 3*DD);
  hipMemcpyAsync(h, nodes, (size_t)NN*DD*4, hipMemcpyDeviceToDevice, stream);

  const int grows = (NN + TM - 1)/TM;
  for (int pass = 0; pass < NPASS; pass++) {
    gemm_msg<true ><<<grows, 256, 0, stream>>>(h, srcS, off, deg, b_e, WpE, inc, 0);
    for (int t = 1; t < NT; t++)
      gemm_msg<false><<<grows, 256, 0, stream>>>(h, srcS, off, deg, b_e,
                                                 WpE + (size_t)t*DD*WPS, inc, t);
    for (int c = 0; c < NN; c += chunkM) {
      const int m = (NN - c < chunkM) ? (NN - c) : chunkM;
      const int gb = (m + TM - 1)/TM;
      gemm_lin<<<dim3(gb,3), 256, 0, stream>>>(inc + (size_t)c*DD, WpI, GI, b_ih, m, 3*DD);
      gemm_lin<<<dim3(gb,3), 256, 0, stream>>>(h   + (size_t)c*DD, WpH, GH, b_hh, m, 3*DD);
      gru_kernel<<<(int)(((size_t)m*(DD/2) + 255)/256), 256, 0, stream>>>(GI, GH, h, c, m);
    }
  }

  readout1<<<NG*RPB, 256, 0, stream>>>(h, gids, part);
  readout2<<<NG, 256, 0, stream>>>(part, pclass, xbuf);
  fc1_kernel<<<NG, HIDN, 0, stream>>>(xbuf, fc1w, fc1b, hidb);
  fc2_kernel<<<NG, 64, 0, stream>>>(hidb, fc2w, fc2b, out);
}

// Round 5
// 12909.915 us; speedup vs baseline: 3.4542x; 1.6958x over previous
//
#include <hip/hip_runtime.h>
#include <cstdint>
#include <cstddef>

#define NN 100000
#define NE 800000
#define NG 64
#define NT 4
#define DD 150
#define HIDN 512
#define NPASS 5
#define NBINS (NN*NT)
#define TM 64      // A-tile rows: LDS 64*151*4 = 38656 B -> 4 blocks/CU
#define LDA 151    // LDS tile row stride (2-way bank pattern -> free)
#define WPS 152    // padded W row stride (floats): rows 16B-aligned for float4 loads
#define RPB 16     // readout partial blocks per graph
#define CHUNK_CAP 25024  // GI+GH <= 2*25024*450*4 = 90 MB -> LLC-resident

static __device__ __forceinline__ float sigmoidf_(float x){ return 1.f/(1.f+expf(-x)); }

// ---------------- setup: counting sort of edges by (dst,type) ----------------

__global__ void count_kernel(const int* __restrict__ dst, const int* __restrict__ typ,
                             unsigned* __restrict__ deg){
  int e = blockIdx.x*256 + threadIdx.x;
  if (e < NE) atomicAdd(&deg[dst[e]*NT + typ[e]], 1u);
}

__device__ unsigned block_excl_base(unsigned threadSum){
  const int tid = threadIdx.x;
  const int lane = tid & 63, wid = tid >> 6;
  unsigned s = threadSum;
  #pragma unroll
  for (int d = 1; d < 64; d <<= 1){ unsigned t = __shfl_up(s, d); if (lane >= d) s += t; }
  __shared__ unsigned wsum[4];
  if (lane == 63) wsum[wid] = s;
  __syncthreads();
  unsigned base = 0;
  for (int w = 0; w < wid; w++) base += wsum[w];
  return base + s - threadSum;
}

__global__ void scan_reduce(const unsigned* __restrict__ deg, unsigned* __restrict__ bsum){
  const int base = blockIdx.x*1024 + threadIdx.x*4;
  unsigned s = 0;
  #pragma unroll
  for (int i = 0; i < 4; i++){ const int idx = base+i; if (idx < NBINS) s += deg[idx]; }
  #pragma unroll
  for (int d = 1; d < 64; d <<= 1) s += __shfl_down(s, d);
  __shared__ unsigned ws4[4];
  const int lane = threadIdx.x & 63, wid = threadIdx.x >> 6;
  if (lane == 0) ws4[wid] = s;
  __syncthreads();
  if (threadIdx.x == 0) bsum[blockIdx.x] = ws4[0]+ws4[1]+ws4[2]+ws4[3];
}

__global__ void scan_block(unsigned* bsum, int n){
  const int tid = threadIdx.x;
  unsigned v[4]; unsigned s = 0;
  #pragma unroll
  for (int i = 0; i < 4; i++){ const int idx = tid*4+i; v[i] = (idx < n) ? bsum[idx] : 0u; s += v[i]; }
  unsigned run = block_excl_base(s);
  #pragma unroll
  for (int i = 0; i < 4; i++){ const int idx = tid*4+i; if (idx < n) bsum[idx] = run; run += v[i]; }
}

__global__ void scan_final(const unsigned* __restrict__ deg, const unsigned* __restrict__ bsum,
                           unsigned* __restrict__ off){
  const int tid = threadIdx.x;
  const int base0 = blockIdx.x*1024 + tid*4;
  unsigned v[4]; unsigned s = 0;
  #pragma unroll
  for (int i = 0; i < 4; i++){ const int idx = base0+i; v[i] = (idx < NBINS) ? deg[idx] : 0u; s += v[i]; }
  unsigned run = block_excl_base(s) + bsum[blockIdx.x];
  #pragma unroll
  for (int i = 0; i < 4; i++){ const int idx = base0+i; if (idx < NBINS) off[idx] = run; run += v[i]; }
  if (blockIdx.x == 0 && tid == 0) off[NBINS] = NE;
}

__global__ void scatter_sort(const int* __restrict__ src, const int* __restrict__ dst,
                             const int* __restrict__ typ, unsigned* __restrict__ cur,
                             int* __restrict__ srcSorted){
  int e = blockIdx.x*256 + threadIdx.x;
  if (e < NE){
    const int bin = dst[e]*NT + typ[e];
    const unsigned p = atomicAdd(&cur[bin], 1u);
    srcSorted[p] = src[e];
  }
}

__global__ void padW(const float* __restrict__ W, float* __restrict__ Wp, int rows){
  int idx = blockIdx.x*256 + threadIdx.x;
  if (idx < rows*DD){ const int n = idx/DD, k = idx - n*DD; Wp[n*WPS + k] = W[idx]; }
}

// ---------------- GEMM core: 64-row A-tile in LDS, W streamed from global ----------------
// thread-tile: 4 rows (4*tm..4*tm+3) x 10 cols (16*j + tn), 256 threads.

#define GEMM_COMPUTE_BODY(Ab, Wb) \
  _Pragma("unroll 2") \
  for (int k4 = 0; k4 < 37; k4++){ \
    const int k = 4*k4; \
    float a[4][4]; \
    _Pragma("unroll") \
    for (int r = 0; r < 4; r++){ \
      a[r][0]=Ab[r*LDA+k];   a[r][1]=Ab[r*LDA+k+1]; \
      a[r][2]=Ab[r*LDA+k+2]; a[r][3]=Ab[r*LDA+k+3]; } \
    _Pragma("unroll") \
    for (int j = 0; j < 10; j++){ \
      const int n = 16*j + tn; \
      if (n < DD){ \
        const float4 w = *(const float4*)(Wb + (size_t)n*WPS + k); \
        _Pragma("unroll") \
        for (int r = 0; r < 4; r++) \
          acc[r][j] = fmaf(a[r][0], w.x, fmaf(a[r][1], w.y, \
                      fmaf(a[r][2], w.z, fmaf(a[r][3], w.w, acc[r][j])))); } } } \
  { /* k tail: 148, 149 */ \
    float a[4][2]; \
    _Pragma("unroll") \
    for (int r = 0; r < 4; r++){ a[r][0]=Ab[r*LDA+148]; a[r][1]=Ab[r*LDA+149]; } \
    _Pragma("unroll") \
    for (int j = 0; j < 10; j++){ \
      const int n = 16*j + tn; \
      if (n < DD){ \
        const float2 w = *(const float2*)(Wb + (size_t)n*WPS + 148); \
        _Pragma("unroll") \
        for (int r = 0; r < 4; r++) \
          acc[r][j] = fmaf(a[r][0], w.x, fmaf(a[r][1], w.y, acc[r][j])); } } }

// park acc into LDS C-tile (reuses As), then coalesced global stores
#define GEMM_PARK_ACC(Asr) \
  __syncthreads();  /* all done reading As */ \
  _Pragma("unroll") \
  for (int r = 0; r < 4; r++){ \
    _Pragma("unroll") \
    for (int j = 0; j < 10; j++){ \
      const int n = 16*j + tn; \
      if (n < DD) Asr[(4*tm+r)*LDA + n] = acc[r][j]; } } \
  __syncthreads();

// message kernel (one edge type): INIT -> inc = deg@b_e + agg@W^T ; else inc += agg@W^T
template<bool INIT>
__global__ __launch_bounds__(256, 4) void gemm_msg(
    const float* __restrict__ h, const int* __restrict__ srcSorted,
    const unsigned* __restrict__ off, const unsigned* __restrict__ deg,
    const float* __restrict__ b_e, const float* __restrict__ Wb,
    float* __restrict__ inc, int typeT)
{
  __shared__ float As[TM*LDA];
  const int tid = threadIdx.x;
  const int rowTile = blockIdx.x * TM;
  const int lane = tid & 63, sub = tid >> 6;

  { // gather-stage agg tile: 4 sub-waves x 16 rows each
    #pragma unroll
    for (int i = 0; i < TM/4; i++){
      const int m = sub*(TM/4) + i;
      const int node = rowTile + m;
      float a0 = 0.f, a1 = 0.f, a2 = 0.f;
      if (node < NN){
        const int bin = node*NT + typeT;
        const unsigned lo = off[bin], hi = off[bin+1];
        for (unsigned e = lo; e < hi; e++){
          const int s = srcSorted[e];
          const float* hp = h + (size_t)s*DD;
          a0 += hp[lane];
          a1 += hp[lane+64];
          if (lane < DD-128) a2 += hp[lane+128];
        }
      }
      As[m*LDA + lane]      = a0;
      As[m*LDA + 64 + lane] = a1;
      if (lane < DD-128) As[m*LDA + 128 + lane] = a2;
    }
  }
  __syncthreads();

  const int tm = tid & 15, tn = tid >> 4;
  float acc[4][10];
  #pragma unroll
  for (int r = 0; r < 4; r++)
    #pragma unroll
    for (int j = 0; j < 10; j++) acc[r][j] = 0.f;

  const float* Ab = &As[(4*tm)*LDA];
  GEMM_COMPUTE_BODY(Ab, Wb)
  GEMM_PARK_ACC(As)

  // coalesced epilogue: sub-wave s stores rows s*16..s*16+15, lane -> col
  #pragma unroll
  for (int i = 0; i < TM/4; i++){
    const int m = sub*(TM/4) + i;
    const int row = rowTile + m;
    if (row < NN){
      float v0 = As[m*LDA + lane];
      float v1 = As[m*LDA + 64 + lane];
      float v2 = (lane < DD-128) ? As[m*LDA + 128 + lane] : 0.f;
      float* op = inc + (size_t)row*DD;
      if (INIT){
        const uint4 dg = *(const uint4*)(&deg[row*NT]);
        const float d0=(float)dg.x, d1=(float)dg.y, d2=(float)dg.z, d3=(float)dg.w;
        v0 += fmaf(d0, b_e[lane],     fmaf(d1, b_e[DD+lane],
              fmaf(d2, b_e[2*DD+lane],     d3*b_e[3*DD+lane])));
        v1 += fmaf(d0, b_e[lane+64],  fmaf(d1, b_e[DD+lane+64],
              fmaf(d2, b_e[2*DD+lane+64],  d3*b_e[3*DD+lane+64])));
        if (lane < DD-128)
          v2 += fmaf(d0, b_e[lane+128], fmaf(d1, b_e[DD+lane+128],
                fmaf(d2, b_e[2*DD+lane+128], d3*b_e[3*DD+lane+128])));
        op[lane]      = v0;
        op[64+lane]   = v1;
        if (lane < DD-128) op[128+lane] = v2;
      } else {
        op[lane]      += v0;
        op[64+lane]   += v1;
        if (lane < DD-128) op[128+lane] += v2;
      }
    }
  }
}

// plain gemm: C[row, col0+n] = A[row,:]@W[col0+n,:] + bias
__global__ __launch_bounds__(256, 4) void gemm_lin(
    const float* __restrict__ A, const float* __restrict__ Wp,
    float* __restrict__ C, const float* __restrict__ bias, int M, int ldc)
{
  __shared__ float As[TM*LDA];
  const int tid = threadIdx.x;
  const int rowTile = blockIdx.x * TM;
  const float* __restrict__ Wb = Wp + (size_t)blockIdx.y * (DD*WPS);
  const int col0 = blockIdx.y * DD;
  const int lane = tid & 63, sub = tid >> 6;

  // stage A tile: float2 loads (rows are 600 B stride -> 8 B aligned)
  for (int i2 = tid; i2 < TM*(DD/2); i2 += 256){
    const int m = i2 / (DD/2), kk2 = i2 - m*(DD/2);
    const int k = 2*kk2;
    const int row = rowTile + m;
    float2 v = make_float2(0.f, 0.f);
    if (row < M) v = *(const float2*)(A + (size_t)row*DD + k);
    As[m*LDA + k]   = v.x;
    As[m*LDA + k+1] = v.y;
  }
  __syncthreads();

  const int tm = tid & 15, tn = tid >> 4;
  float acc[4][10];
  #pragma unroll
  for (int r = 0; r < 4; r++)
    #pragma unroll
    for (int j = 0; j < 10; j++) acc[r][j] = 0.f;

  const float* Ab = &As[(4*tm)*LDA];
  GEMM_COMPUTE_BODY(Ab, Wb)
  GEMM_PARK_ACC(As)

  // coalesced epilogue with bias
  #pragma unroll
  for (int i = 0; i < TM/4; i++){
    const int m = sub*(TM/4) + i;
    const int row = rowTile + m;
    if (row < M){
      float* op = C + (size_t)row*ldc + col0;
      op[lane]    = As[m*LDA + lane]      + bias[col0 + lane];
      op[64+lane] = As[m*LDA + 64 + lane] + bias[col0 + 64 + lane];
      if (lane < DD-128)
        op[128+lane] = As[m*LDA + 128 + lane] + bias[col0 + 128 + lane];
    }
  }
}

// ---------------- GRU elementwise (float2; gate order r,z,n) ----------------
__global__ void gru_kernel(const float* __restrict__ GI, const float* __restrict__ GH,
                           float* __restrict__ h, int c0, int m){
  const int idx = blockIdx.x*256 + threadIdx.x;
  if (idx >= m*(DD/2)) return;
  const int i = idx / (DD/2), d = (idx - i*(DD/2))*2;
  const float* gi = GI + (size_t)i*3*DD;
  const float* gh = GH + (size_t)i*3*DD;
  const float2 ir = *(const float2*)(gi + d);
  const float2 iz = *(const float2*)(gi + DD + d);
  const float2 in = *(const float2*)(gi + 2*DD + d);
  const float2 hr = *(const float2*)(gh + d);
  const float2 hz = *(const float2*)(gh + DD + d);
  const float2 hn = *(const float2*)(gh + 2*DD + d);
  float* hp = h + (size_t)(c0+i)*DD + d;
  const float2 hv = *(const float2*)hp;
  float2 o;
  { const float r = sigmoidf_(ir.x + hr.x), z = sigmoidf_(iz.x + hz.x);
    const float n = tanhf(in.x + r*hn.x); o.x = (1.f - z)*n + z*hv.x; }
  { const float r = sigmoidf_(ir.y + hr.y), z = sigmoidf_(iz.y + hz.y);
    const float n = tanhf(in.y + r*hn.y); o.y = (1.f - z)*n + z*hv.y; }
  *(float2*)hp = o;
}

// ---------------- readout: two-stage segment sum, log/nan/relu, concat ----------------
__global__ void readout1(const float* __restrict__ h, const int* __restrict__ gids,
                         float* __restrict__ part){
  const int g = blockIdx.x >> 4, s = blockIdx.x & (RPB-1);
  const int tid = threadIdx.x;
  __shared__ int sb[2];
  if (tid < 2){
    const int target = g + tid;
    int lo = 0, hi = NN;
    while (lo < hi){ const int mid = (lo+hi) >> 1; if (gids[mid] < target) lo = mid+1; else hi = mid; }
    sb[tid] = lo;
  }
  __syncthreads();
  const int lo = sb[0], hi = sb[1];
  const int len = hi - lo;
  const int per = (len + RPB - 1) / RPB;
  const int nlo = lo + s*per;
  const int nhi = (nlo + per < hi) ? (nlo + per) : hi;
  if (tid < DD){
    float acc = 0.f;
    for (int n = nlo; n < nhi; n++) acc += h[(size_t)n*DD + tid];
    part[(size_t)blockIdx.x*DD + tid] = acc;
  }
}

__global__ void readout2(const float* __restrict__ part, const float* __restrict__ pclass,
                         float* __restrict__ xbuf){
  const int g = blockIdx.x, tid = threadIdx.x;
  if (tid < DD){
    float acc = 0.f;
    #pragma unroll
    for (int s = 0; s < RPB; s++) acc += part[(size_t)(g*RPB + s)*DD + tid];
    float l = logf(acc);            // log(neg)=NaN, log(0)=-inf
    if (isnan(l)) l = 0.f;          // nan -> 0
    l = fmaxf(l, 0.f);              // relu (also kills -inf)
    xbuf[g*(DD+1)+tid] = l;
  }
  if (tid == DD) xbuf[g*(DD+1)+DD] = pclass[g];
}

__global__ void fc1_kernel(const float* __restrict__ xbuf, const float* __restrict__ w,
                           const float* __restrict__ b, float* __restrict__ hid){
  const int g = blockIdx.x, tid = threadIdx.x;   // 512 threads
  __shared__ float xs[DD+1];
  if (tid < DD+1) xs[tid] = xbuf[g*(DD+1)+tid];
  __syncthreads();
  float acc = b[tid];
  for (int k = 0; k < DD+1; k++) acc = fmaf(xs[k], w[k*HIDN + tid], acc);
  hid[g*HIDN + tid] = (acc > 0.f) ? acc : 0.01f*acc;   // leaky_relu(0.01)
}

__global__ void fc2_kernel(const float* __restrict__ hid, const float* __restrict__ w,
                           const float* __restrict__ b, float* __restrict__ out){
  const int g = blockIdx.x, tid = threadIdx.x;   // 64 threads
  __shared__ float hs[HIDN];
  for (int i = tid; i < HIDN; i += 64) hs[i] = hid[g*HIDN + i];
  __syncthreads();
  if (tid < 10){
    float acc = b[tid];
    for (int k = 0; k < HIDN; k++) acc = fmaf(hs[k], w[k*10 + tid], acc);
    out[g*10 + tid] = acc;
  }
}

// ---------------- host orchestration ----------------
extern "C" void kernel_launch(void* const* d_in, const int* in_sizes, int n_in,
                              void* d_out, int out_size, void* d_ws, size_t ws_size,
                              hipStream_t stream)
{
  (void)in_sizes; (void)n_in; (void)out_size;
  const float* nodes  = (const float*)d_in[0];
  const float* pclass = (const float*)d_in[1];
  const int*   esrc   = (const int*)d_in[2];
  const int*   edst   = (const int*)d_in[3];
  const int*   etyp   = (const int*)d_in[4];
  const int*   gids   = (const int*)d_in[5];
  const float* W_e    = (const float*)d_in[6];
  const float* b_e    = (const float*)d_in[7];
  const float* w_ih   = (const float*)d_in[8];
  const float* w_hh   = (const float*)d_in[9];
  const float* b_ih   = (const float*)d_in[10];
  const float* b_hh   = (const float*)d_in[11];
  const float* fc1w   = (const float*)d_in[12];
  const float* fc1b   = (const float*)d_in[13];
  const float* fc2w   = (const float*)d_in[14];
  const float* fc2b   = (const float*)d_in[15];
  float* out = (float*)d_out;

  char* p = (char*)d_ws;
  auto alloc = [&](size_t bytes)->char* {
    char* r = p; p += ((bytes + 255) & ~(size_t)255); return r;
  };
  float*    h    = (float*)alloc((size_t)NN*DD*4);          // 60 MB
  float*    inc  = (float*)alloc((size_t)NN*DD*4);          // 60 MB
  unsigned* deg  = (unsigned*)alloc((size_t)NBINS*4);
  unsigned* off  = (unsigned*)alloc((size_t)(NBINS+1)*4);
  unsigned* cur  = (unsigned*)alloc((size_t)NBINS*4);
  unsigned* bsum = (unsigned*)alloc(4096);
  int*      srcS = (int*)alloc((size_t)NE*4);
  float*    WpE  = (float*)alloc((size_t)NT*DD*WPS*4);
  float*    WpI  = (float*)alloc((size_t)3*DD*WPS*4);
  float*    WpH  = (float*)alloc((size_t)3*DD*WPS*4);
  float*    part = (float*)alloc((size_t)NG*RPB*DD*4);
  float*    xbuf = (float*)alloc((size_t)NG*(DD+1)*4);
  float*    hidb = (float*)alloc((size_t)NG*HIDN*4);

  const size_t used = (size_t)(p - (char*)d_ws);
  const size_t remain = (ws_size > used) ? (ws_size - used) : 0;
  long long cm = (long long)(remain / (2ull*3*DD*4));
  if (cm > CHUNK_CAP) cm = CHUNK_CAP;   // keep GI/GH LLC-resident (<= 90 MB)
  cm &= ~63LL;
  if (cm < 64) cm = 64;
  const int chunkM = (int)cm;
  float* GI = (float*)p;
  float* GH = GI + (size_t)chunkM*3*DD;

  // --- per-launch setup (edge CSR sort + padded weights + h init) ---
  hipMemsetAsync(deg, 0, (size_t)NBINS*4, stream);
  count_kernel<<<(NE+255)/256, 256, 0, stream>>>(edst, etyp, deg);
  const int SCB = (NBINS + 1023)/1024;   // 391
  scan_reduce<<<SCB, 256, 0, stream>>>(deg, bsum);
  scan_block<<<1, 256, 0, stream>>>(bsum, SCB);
  scan_final<<<SCB, 256, 0, stream>>>(deg, bsum, off);
  hipMemcpyAsync(cur, off, (size_t)NBINS*4, hipMemcpyDeviceToDevice, stream);
  scatter_sort<<<(NE+255)/256, 256, 0, stream>>>(esrc, edst, etyp, cur, srcS);
  padW<<<(NT*DD*DD+255)/256, 256, 0, stream>>>(W_e, WpE, NT*DD);
  padW<<<(3*DD*DD+255)/256, 256, 0, stream>>>(w_ih, WpI, 3*DD);
  padW<<<(3*DD*DD+255)/256, 256, 0, stream>>>(w_hh, WpH, 3*DD);
  hipMemcpyAsync(h, nodes, (size_t)NN*DD*4, hipMemcpyDeviceToDevice, stream);

  const int grows = (NN + TM - 1)/TM;
  for (int pass = 0; pass < NPASS; pass++) {
    gemm_msg<true ><<<grows, 256, 0, stream>>>(h, srcS, off, deg, b_e, WpE, inc, 0);
    for (int t = 1; t < NT; t++)
      gemm_msg<false><<<grows, 256, 0, stream>>>(h, srcS, off, deg, b_e,
                                                 WpE + (size_t)t*DD*WPS, inc, t);
    for (int c = 0; c < NN; c += chunkM) {
      const int m = (NN - c < chunkM) ? (NN - c) : chunkM;
      const int gb = (m + TM - 1)/TM;
      gemm_lin<<<dim3(gb,3), 256, 0, stream>>>(inc + (size_t)c*DD, WpI, GI, b_ih, m, 3*DD);
      gemm_lin<<<dim3(gb,3), 256, 0, stream>>>(h   + (size_t)c*DD, WpH, GH, b_hh, m, 3*DD);
      gru_kernel<<<(int)(((size_t)m*(DD/2) + 255)/256), 256, 0, stream>>>(GI, GH, h, c, m);
    }
  }

  readout1<<<NG*RPB, 256, 0, stream>>>(h, gids, part);
  readout2<<<NG, 256, 0, stream>>>(part, pclass, xbuf);
  fc1_kernel<<<NG, HIDN, 0, stream>>>(xbuf, fc1w, fc1b, hidb);
  fc2_kernel<<<NG, 64, 0, stream>>>(hidb, fc2w, fc2b, out);
}

// Round 7
// 3767.307 us; speedup vs baseline: 11.8371x; 3.4268x over previous
//
#include <hip/hip_runtime.h>
#include <hip/hip_bf16.h>
#include <cstdint>
#include <cstddef>

#define NN 100000
#define NE 800000
#define NG 64
#define NT 4
#define DD 150
#define HIDN 512
#define NPASS 5
#define NBINS (NN*NT)
#define RPB 16     // readout partial blocks per graph

typedef short  s8v  __attribute__((ext_vector_type(8)));   // 8 bf16 (4 VGPRs)
typedef float  f32x4 __attribute__((ext_vector_type(4)));

static __device__ __forceinline__ float sigmoidf_(float x){ return 1.f/(1.f+expf(-x)); }
static __device__ __forceinline__ short f2bf(float x){
  __hip_bfloat16 b = __float2bfloat16(x);
  return *(short*)&b;
}
static __device__ __forceinline__ float bf2f(short s){
  union { unsigned u; float f; } v; v.u = ((unsigned)(unsigned short)s) << 16; return v.f;
}
// split fp32 into hi bf16 + residual bf16 (Markidis): x ~= hi + lo
static __device__ __forceinline__ void split_bf(float x, short& hi, short& lo){
  hi = f2bf(x);
  lo = f2bf(x - bf2f(hi));
}

// ---------------- setup: counting sort of edges by (dst,type) ----------------

__global__ void count_kernel(const int* __restrict__ dst, const int* __restrict__ typ,
                             unsigned* __restrict__ deg){
  int e = blockIdx.x*256 + threadIdx.x;
  if (e < NE) atomicAdd(&deg[dst[e]*NT + typ[e]], 1u);
}

__device__ unsigned block_excl_base(unsigned threadSum){
  const int tid = threadIdx.x;
  const int lane = tid & 63, wid = tid >> 6;
  unsigned s = threadSum;
  #pragma unroll
  for (int d = 1; d < 64; d <<= 1){ unsigned t = __shfl_up(s, d); if (lane >= d) s += t; }
  __shared__ unsigned wsum[4];
  if (lane == 63) wsum[wid] = s;
  __syncthreads();
  unsigned base = 0;
  for (int w = 0; w < wid; w++) base += wsum[w];
  return base + s - threadSum;
}

__global__ void scan_reduce(const unsigned* __restrict__ deg, unsigned* __restrict__ bsum){
  const int base = blockIdx.x*1024 + threadIdx.x*4;
  unsigned s = 0;
  #pragma unroll
  for (int i = 0; i < 4; i++){ const int idx = base+i; if (idx < NBINS) s += deg[idx]; }
  #pragma unroll
  for (int d = 1; d < 64; d <<= 1) s += __shfl_down(s, d);
  __shared__ unsigned ws4[4];
  const int lane = threadIdx.x & 63, wid = threadIdx.x >> 6;
  if (lane == 0) ws4[wid] = s;
  __syncthreads();
  if (threadIdx.x == 0) bsum[blockIdx.x] = ws4[0]+ws4[1]+ws4[2]+ws4[3];
}

__global__ void scan_block(unsigned* bsum, int n){
  const int tid = threadIdx.x;
  unsigned v[4]; unsigned s = 0;
  #pragma unroll
  for (int i = 0; i < 4; i++){ const int idx = tid*4+i; v[i] = (idx < n) ? bsum[idx] : 0u; s += v[i]; }
  unsigned run = block_excl_base(s);
  #pragma unroll
  for (int i = 0; i < 4; i++){ const int idx = tid*4+i; if (idx < n) bsum[idx] = run; run += v[i]; }
}

__global__ void scan_final(const unsigned* __restrict__ deg, const unsigned* __restrict__ bsum,
                           unsigned* __restrict__ off){
  const int tid = threadIdx.x;
  const int base0 = blockIdx.x*1024 + tid*4;
  unsigned v[4]; unsigned s = 0;
  #pragma unroll
  for (int i = 0; i < 4; i++){ const int idx = base0+i; v[i] = (idx < NBINS) ? deg[idx] : 0u; s += v[i]; }
  unsigned run = block_excl_base(s) + bsum[blockIdx.x];
  #pragma unroll
  for (int i = 0; i < 4; i++){ const int idx = base0+i; if (idx < NBINS) off[idx] = run; run += v[i]; }
  if (blockIdx.x == 0 && tid == 0) off[NBINS] = NE;
}

__global__ void scatter_sort(const int* __restrict__ src, const int* __restrict__ dst,
                             const int* __restrict__ typ, unsigned* __restrict__ cur,
                             int* __restrict__ srcSorted){
  int e = blockIdx.x*256 + threadIdx.x;
  if (e < NE){
    const int bin = dst[e]*NT + typ[e];
    const unsigned p = atomicAdd(&cur[bin], 1u);
    srcSorted[p] = src[e];
  }
}

// ---------------- pack W [groups*150][150] fp32 -> bf16 hi/lo B-fragments ----------
// layout: frag (g, i=coltile<10, s=kstep<5): 64 lanes x 8 bf16; lane l, elem j holds
// B[k=32s+(l>>4)*8+j][n=16i+(l&15)] = W[g*150 + n][k]  (0 beyond 150)
__global__ void build_bfrag(const float* __restrict__ W, unsigned short* __restrict__ out_hi,
                            unsigned short* __restrict__ out_lo, int groups){
  const int idx = blockIdx.x*256 + threadIdx.x;
  const int total = groups*10*5*512;
  if (idx >= total) return;
  const int j = idx & 7, l = (idx>>3) & 63;
  const int fi = idx >> 9;          // (g*10+i)*5+s
  const int s = fi % 5;
  const int i = (fi/5) % 10;
  const int g = fi / 50;
  const int n = 16*i + (l & 15);
  const int k = 32*s + (l>>4)*8 + j;
  float v = 0.f;
  if (n < DD && k < DD) v = W[((size_t)(g*DD + n))*DD + k];
  short hi, lo; split_bf(v, hi, lo);
  out_hi[idx] = (unsigned short)hi;
  out_lo[idx] = (unsigned short)lo;
}

// 3-product split-precision accumulate: acc += (Ahi+Alo)*(Bhi+Blo) minus lo*lo
#define MFMA3(acc, ahi, alo, bhi, blo) \
  acc = __builtin_amdgcn_mfma_f32_16x16x32_bf16(ahi, bhi, acc, 0,0,0); \
  acc = __builtin_amdgcn_mfma_f32_16x16x32_bf16(alo, bhi, acc, 0,0,0); \
  acc = __builtin_amdgcn_mfma_f32_16x16x32_bf16(ahi, blo, acc, 0,0,0);

// ---------------- message kernel: inc = deg@b_e + sum_t agg_t @ W_t^T (MFMA) -------
// Block = 4 waves; wave handles rows [blk*64+wave*16, +16), all 150 cols.
__global__ __launch_bounds__(256, 3) void mfma_msg(
    const float* __restrict__ h, const int* __restrict__ srcS,
    const unsigned* __restrict__ off, const unsigned* __restrict__ deg,
    const float* __restrict__ b_e,
    const unsigned short* __restrict__ BfE_hi, const unsigned short* __restrict__ BfE_lo,
    float* __restrict__ inc)
{
  const int tid = threadIdx.x, wave = tid >> 6, l = tid & 63;
  const int m = l & 15, q = l >> 4;
  const int arow = blockIdx.x*64 + wave*16 + m;   // this lane's A-row
  const int q8 = q*8;

  f32x4 acc[10];
  #pragma unroll
  for (int i = 0; i < 10; i++) acc[i] = (f32x4)(0.0f);

  for (int t = 0; t < NT; t++){
    // gather A-fragments fp32: lane sums h[src][32s+q8+j]
    float a[5][8];
    #pragma unroll
    for (int s = 0; s < 5; s++)
      #pragma unroll
      for (int j = 0; j < 8; j++) a[s][j] = 0.f;

    unsigned lo = 0, hi = 0;
    if (arow < NN){ const int bin = arow*NT + t; lo = off[bin]; hi = off[bin+1]; }
    for (unsigned e = lo; e < hi; e++){
      const int src = srcS[e];
      const float* hp = h + (size_t)src*DD;
      #pragma unroll
      for (int s = 0; s < 4; s++){
        const int b = 32*s + q8;
        const float2 v0 = *(const float2*)(hp+b),   v1 = *(const float2*)(hp+b+2);
        const float2 v2 = *(const float2*)(hp+b+4), v3 = *(const float2*)(hp+b+6);
        a[s][0]+=v0.x; a[s][1]+=v0.y; a[s][2]+=v1.x; a[s][3]+=v1.y;
        a[s][4]+=v2.x; a[s][5]+=v2.y; a[s][6]+=v3.x; a[s][7]+=v3.y;
      }
      { // s=4: b = 128+q8; q<2 full, q==2 -> 6 elems, q==3 -> none
        const int b = 128 + q8;
        if (q < 2){
          const float2 v0 = *(const float2*)(hp+b),   v1 = *(const float2*)(hp+b+2);
          const float2 v2 = *(const float2*)(hp+b+4), v3 = *(const float2*)(hp+b+6);
          a[4][0]+=v0.x; a[4][1]+=v0.y; a[4][2]+=v1.x; a[4][3]+=v1.y;
          a[4][4]+=v2.x; a[4][5]+=v2.y; a[4][6]+=v3.x; a[4][7]+=v3.y;
        } else if (q == 2){
          const float2 v0 = *(const float2*)(hp+b), v1 = *(const float2*)(hp+b+2);
          const float2 v2 = *(const float2*)(hp+b+4);
          a[4][0]+=v0.x; a[4][1]+=v0.y; a[4][2]+=v1.x; a[4][3]+=v1.y;
          a[4][4]+=v2.x; a[4][5]+=v2.y;
        }
      }
    }

    s8v af_hi[5], af_lo[5];
    #pragma unroll
    for (int s = 0; s < 5; s++)
      #pragma unroll
      for (int j = 0; j < 8; j++){
        short hi2, lo2; split_bf(a[s][j], hi2, lo2);
        af_hi[s][j] = hi2; af_lo[s][j] = lo2;
      }

    const unsigned short* bbh = BfE_hi + (size_t)(t*50)*512 + (size_t)l*8;
    const unsigned short* bbl = BfE_lo + (size_t)(t*50)*512 + (size_t)l*8;
    #pragma unroll
    for (int i = 0; i < 10; i++){
      #pragma unroll
      for (int s = 0; s < 5; s++){
        const s8v bh = *(const s8v*)(bbh + (i*5 + s)*512);
        const s8v bl = *(const s8v*)(bbl + (i*5 + s)*512);
        MFMA3(acc[i], af_hi[s], af_lo[s], bh, bl)
      }
    }
  }

  // epilogue: C[crow][16i+m], crow = blk*64+wave*16+q*4+r ; add deg@b_e bias
  const int crow0 = blockIdx.x*64 + wave*16 + q*4;
  #pragma unroll
  for (int r = 0; r < 4; r++){
    const int crow = crow0 + r;
    if (crow < NN){
      const uint4 dg = *(const uint4*)(&deg[crow*NT]);
      const float d0=(float)dg.x, d1=(float)dg.y, d2=(float)dg.z, d3=(float)dg.w;
      float* op = inc + (size_t)crow*DD;
      #pragma unroll
      for (int i = 0; i < 10; i++){
        const int c = 16*i + m;
        if (c < DD){
          const float bias = fmaf(d0, b_e[c], fmaf(d1, b_e[DD+c],
                             fmaf(d2, b_e[2*DD+c], d3*b_e[3*DD+c])));
          op[c] = acc[i][r] + bias;
        }
      }
    }
  }
}

// ---------------- fused gi/gh GEMM + GRU: hnext = GRU(inc, hcur) --------------------
__global__ __launch_bounds__(256, 2) void mfma_lingru(
    const float* __restrict__ inc, const float* __restrict__ hcur,
    const unsigned short* __restrict__ BfI_hi, const unsigned short* __restrict__ BfI_lo,
    const unsigned short* __restrict__ BfH_hi, const unsigned short* __restrict__ BfH_lo,
    const float* __restrict__ b_ih, const float* __restrict__ b_hh,
    float* __restrict__ hnext)
{
  const int tid = threadIdx.x, wave = tid >> 6, l = tid & 63;
  const int m = l & 15, q = l >> 4;
  const int arow = blockIdx.x*64 + wave*16 + m;
  const int q8 = q*8;
  const bool av = (arow < NN);

  // load A-fragments for inc and h rows (fp32 -> bf16 hi/lo split)
  s8v afi_h[5], afi_l[5], afh_h[5], afh_l[5];
  {
    const float* ip = inc  + (size_t)(av ? arow : 0)*DD;
    const float* hp = hcur + (size_t)(av ? arow : 0)*DD;
    #pragma unroll
    for (int s = 0; s < 5; s++){
      float ti[8] = {0,0,0,0,0,0,0,0}, th[8] = {0,0,0,0,0,0,0,0};
      const int b = 32*s + q8;
      if (av){
        if (b + 8 <= DD){
          const float2 u0=*(const float2*)(ip+b),   u1=*(const float2*)(ip+b+2);
          const float2 u2=*(const float2*)(ip+b+4), u3=*(const float2*)(ip+b+6);
          ti[0]=u0.x; ti[1]=u0.y; ti[2]=u1.x; ti[3]=u1.y; ti[4]=u2.x; ti[5]=u2.y; ti[6]=u3.x; ti[7]=u3.y;
          const float2 w0=*(const float2*)(hp+b),   w1=*(const float2*)(hp+b+2);
          const float2 w2=*(const float2*)(hp+b+4), w3=*(const float2*)(hp+b+6);
          th[0]=w0.x; th[1]=w0.y; th[2]=w1.x; th[3]=w1.y; th[4]=w2.x; th[5]=w2.y; th[6]=w3.x; th[7]=w3.y;
        } else if (b < DD){   // b==144: 6 elems
          const float2 u0=*(const float2*)(ip+b), u1=*(const float2*)(ip+b+2), u2=*(const float2*)(ip+b+4);
          ti[0]=u0.x; ti[1]=u0.y; ti[2]=u1.x; ti[3]=u1.y; ti[4]=u2.x; ti[5]=u2.y;
          const float2 w0=*(const float2*)(hp+b), w1=*(const float2*)(hp+b+2), w2=*(const float2*)(hp+b+4);
          th[0]=w0.x; th[1]=w0.y; th[2]=w1.x; th[3]=w1.y; th[4]=w2.x; th[5]=w2.y;
        }
      }
      #pragma unroll
      for (int j = 0; j < 8; j++){
        short hi2, lo2;
        split_bf(ti[j], hi2, lo2); afi_h[s][j] = hi2; afi_l[s][j] = lo2;
        split_bf(th[j], hi2, lo2); afh_h[s][j] = hi2; afh_l[s][j] = lo2;
      }
    }
  }

  const int crow0 = blockIdx.x*64 + wave*16 + q*4;
  const size_t lb = (size_t)l*8;

  for (int iT = 0; iT < 10; iT++){
    f32x4 gi0=(f32x4)(0.f), gi1=(f32x4)(0.f), gi2=(f32x4)(0.f);
    f32x4 gh0=(f32x4)(0.f), gh1=(f32x4)(0.f), gh2=(f32x4)(0.f);
    {
      const size_t o0 = (size_t)((0*10+iT)*5)*512 + lb;
      const size_t o1 = (size_t)((1*10+iT)*5)*512 + lb;
      const size_t o2 = (size_t)((2*10+iT)*5)*512 + lb;
      #pragma unroll
      for (int s = 0; s < 5; s++){
        const size_t so = (size_t)s*512;
        const s8v bI0h=*(const s8v*)(BfI_hi+o0+so), bI0l=*(const s8v*)(BfI_lo+o0+so);
        const s8v bH0h=*(const s8v*)(BfH_hi+o0+so), bH0l=*(const s8v*)(BfH_lo+o0+so);
        MFMA3(gi0, afi_h[s], afi_l[s], bI0h, bI0l)
        MFMA3(gh0, afh_h[s], afh_l[s], bH0h, bH0l)
        const s8v bI1h=*(const s8v*)(BfI_hi+o1+so), bI1l=*(const s8v*)(BfI_lo+o1+so);
        const s8v bH1h=*(const s8v*)(BfH_hi+o1+so), bH1l=*(const s8v*)(BfH_lo+o1+so);
        MFMA3(gi1, afi_h[s], afi_l[s], bI1h, bI1l)
        MFMA3(gh1, afh_h[s], afh_l[s], bH1h, bH1l)
        const s8v bI2h=*(const s8v*)(BfI_hi+o2+so), bI2l=*(const s8v*)(BfI_lo+o2+so);
        const s8v bH2h=*(const s8v*)(BfH_hi+o2+so), bH2l=*(const s8v*)(BfH_lo+o2+so);
        MFMA3(gi2, afi_h[s], afi_l[s], bI2h, bI2l)
        MFMA3(gh2, afh_h[s], afh_l[s], bH2h, bH2l)
      }
    }
    const int d = 16*iT + m;
    if (d < DD){
      const float bir=b_ih[d], biz=b_ih[DD+d], bin2=b_ih[2*DD+d];
      const float bhr=b_hh[d], bhz=b_hh[DD+d], bhn=b_hh[2*DD+d];
      #pragma unroll
      for (int r = 0; r < 4; r++){
        const int crow = crow0 + r;
        if (crow < NN){
          const float hv = hcur[(size_t)crow*DD + d];
          const float rr = sigmoidf_(gi0[r] + bir + gh0[r] + bhr);
          const float zz = sigmoidf_(gi1[r] + biz + gh1[r] + bhz);
          const float nn = tanhf(gi2[r] + bin2 + rr*(gh2[r] + bhn));
          hnext[(size_t)crow*DD + d] = (1.f - zz)*nn + zz*hv;
        }
      }
    }
  }
}

// ---------------- readout: two-stage segment sum, log/nan/relu, concat ----------------
__global__ void readout1(const float* __restrict__ h, const int* __restrict__ gids,
                         float* __restrict__ part){
  const int g = blockIdx.x >> 4, s = blockIdx.x & (RPB-1);
  const int tid = threadIdx.x;
  __shared__ int sb[2];
  if (tid < 2){
    const int target = g + tid;
    int lo = 0, hi = NN;
    while (lo < hi){ const int mid = (lo+hi) >> 1; if (gids[mid] < target) lo = mid+1; else hi = mid; }
    sb[tid] = lo;
  }
  __syncthreads();
  const int lo = sb[0], hi = sb[1];
  const int len = hi - lo;
  const int per = (len + RPB - 1) / RPB;
  const int nlo = lo + s*per;
  const int nhi = (nlo + per < hi) ? (nlo + per) : hi;
  if (tid < DD){
    float acc = 0.f;
    for (int n = nlo; n < nhi; n++) acc += h[(size_t)n*DD + tid];
    part[(size_t)blockIdx.x*DD + tid] = acc;
  }
}

__global__ void readout2(const float* __restrict__ part, const float* __restrict__ pclass,
                         float* __restrict__ xbuf){
  const int g = blockIdx.x, tid = threadIdx.x;
  if (tid < DD){
    float acc = 0.f;
    #pragma unroll
    for (int s = 0; s < RPB; s++) acc += part[(size_t)(g*RPB + s)*DD + tid];
    float l = logf(acc);            // log(neg)=NaN, log(0)=-inf
    if (isnan(l)) l = 0.f;          // nan -> 0
    l = fmaxf(l, 0.f);              // relu (also kills -inf)
    xbuf[g*(DD+1)+tid] = l;
  }
  if (tid == DD) xbuf[g*(DD+1)+DD] = pclass[g];
}

__global__ void fc1_kernel(const float* __restrict__ xbuf, const float* __restrict__ w,
                           const float* __restrict__ b, float* __restrict__ hid){
  const int g = blockIdx.x, tid = threadIdx.x;   // 512 threads
  __shared__ float xs[DD+1];
  if (tid < DD+1) xs[tid] = xbuf[g*(DD+1)+tid];
  __syncthreads();
  float acc = b[tid];
  for (int k = 0; k < DD+1; k++) acc = fmaf(xs[k], w[k*HIDN + tid], acc);
  hid[g*HIDN + tid] = (acc > 0.f) ? acc : 0.01f*acc;   // leaky_relu(0.01)
}

__global__ void fc2_kernel(const float* __restrict__ hid, const float* __restrict__ w,
                           const float* __restrict__ b, float* __restrict__ out){
  const int g = blockIdx.x, tid = threadIdx.x;   // 64 threads
  __shared__ float hs[HIDN];
  for (int i = tid; i < HIDN; i += 64) hs[i] = hid[g*HIDN + i];
  __syncthreads();
  if (tid < 10){
    float acc = b[tid];
    for (int k = 0; k < HIDN; k++) acc = fmaf(hs[k], w[k*10 + tid], acc);
    out[g*10 + tid] = acc;
  }
}

// ---------------- host orchestration ----------------
extern "C" void kernel_launch(void* const* d_in, const int* in_sizes, int n_in,
                              void* d_out, int out_size, void* d_ws, size_t ws_size,
                              hipStream_t stream)
{
  (void)in_sizes; (void)n_in; (void)out_size; (void)ws_size;
  const float* nodes  = (const float*)d_in[0];
  const float* pclass = (const float*)d_in[1];
  const int*   esrc   = (const int*)d_in[2];
  const int*   edst   = (const int*)d_in[3];
  const int*   etyp   = (const int*)d_in[4];
  const int*   gids   = (const int*)d_in[5];
  const float* W_e    = (const float*)d_in[6];
  const float* b_e    = (const float*)d_in[7];
  const float* w_ih   = (const float*)d_in[8];
  const float* w_hh   = (const float*)d_in[9];
  const float* b_ih   = (const float*)d_in[10];
  const float* b_hh   = (const float*)d_in[11];
  const float* fc1w   = (const float*)d_in[12];
  const float* fc1b   = (const float*)d_in[13];
  const float* fc2w   = (const float*)d_in[14];
  const float* fc2b   = (const float*)d_in[15];
  float* out = (float*)d_out;

  char* p = (char*)d_ws;
  auto alloc = [&](size_t bytes)->char* {
    char* r = p; p += ((bytes + 255) & ~(size_t)255); return r;
  };
  float*    h0   = (float*)alloc((size_t)NN*DD*4);          // 60 MB
  float*    h1   = (float*)alloc((size_t)NN*DD*4);          // 60 MB
  float*    inc  = (float*)alloc((size_t)NN*DD*4);          // 60 MB
  unsigned* deg  = (unsigned*)alloc((size_t)NBINS*4);
  unsigned* off  = (unsigned*)alloc((size_t)(NBINS+1)*4);
  unsigned* cur  = (unsigned*)alloc((size_t)NBINS*4);
  unsigned* bsum = (unsigned*)alloc(4096);
  int*      srcS = (int*)alloc((size_t)NE*4);
  unsigned short* BfEh = (unsigned short*)alloc((size_t)NT*50*512*2);
  unsigned short* BfEl = (unsigned short*)alloc((size_t)NT*50*512*2);
  unsigned short* BfIh = (unsigned short*)alloc((size_t)3*50*512*2);
  unsigned short* BfIl = (unsigned short*)alloc((size_t)3*50*512*2);
  unsigned short* BfHh = (unsigned short*)alloc((size_t)3*50*512*2);
  unsigned short* BfHl = (unsigned short*)alloc((size_t)3*50*512*2);
  float*    part = (float*)alloc((size_t)NG*RPB*DD*4);
  float*    xbuf = (float*)alloc((size_t)NG*(DD+1)*4);
  float*    hidb = (float*)alloc((size_t)NG*HIDN*4);

  // --- per-launch setup: edge CSR sort + fragment-packed weights + h init ---
  hipMemsetAsync(deg, 0, (size_t)NBINS*4, stream);
  count_kernel<<<(NE+255)/256, 256, 0, stream>>>(edst, etyp, deg);
  const int SCB = (NBINS + 1023)/1024;   // 391
  scan_reduce<<<SCB, 256, 0, stream>>>(deg, bsum);
  scan_block<<<1, 256, 0, stream>>>(bsum, SCB);
  scan_final<<<SCB, 256, 0, stream>>>(deg, bsum, off);
  hipMemcpyAsync(cur, off, (size_t)NBINS*4, hipMemcpyDeviceToDevice, stream);
  scatter_sort<<<(NE+255)/256, 256, 0, stream>>>(esrc, edst, etyp, cur, srcS);
  build_bfrag<<<(NT*50*512+255)/256, 256, 0, stream>>>(W_e,  BfEh, BfEl, NT);
  build_bfrag<<<(3*50*512+255)/256, 256, 0, stream>>>(w_ih, BfIh, BfIl, 3);
  build_bfrag<<<(3*50*512+255)/256, 256, 0, stream>>>(w_hh, BfHh, BfHl, 3);
  hipMemcpyAsync(h0, nodes, (size_t)NN*DD*4, hipMemcpyDeviceToDevice, stream);

  float* hb[2] = {h0, h1};
  const int grows = (NN + 63)/64;        // 1563
  for (int pass = 0; pass < NPASS; pass++){
    const float* hc = hb[pass & 1];
    float*       hn = hb[(pass + 1) & 1];
    mfma_msg<<<grows, 256, 0, stream>>>(hc, srcS, off, deg, b_e, BfEh, BfEl, inc);
    mfma_lingru<<<grows, 256, 0, stream>>>(inc, hc, BfIh, BfIl, BfHh, BfHl,
                                           b_ih, b_hh, hn);
  }

  readout1<<<NG*RPB, 256, 0, stream>>>(hb[NPASS & 1], gids, part);
  readout2<<<NG, 256, 0, stream>>>(part, pclass, xbuf);
  fc1_kernel<<<NG, HIDN, 0, stream>>>(xbuf, fc1w, fc1b, hidb);
  fc2_kernel<<<NG, 64, 0, stream>>>(hidb, fc2w, fc2b, out);
}

// Round 8
// 3636.141 us; speedup vs baseline: 12.2641x; 1.0361x over previous
//
#include <hip/hip_runtime.h>
#include <hip/hip_bf16.h>
#include <cstdint>
#include <cstddef>

#define NN 100000
#define NE 800000
#define NG 64
#define NT 4
#define DD 150
#define HIDN 512
#define NPASS 5
#define NBINS (NN*NT)
#define RPB 16     // readout partial blocks per graph
#define PKS 154    // park-tile row stride: 4*PKS%32==8 -> exactly 2 lanes/bank (free)

typedef short  s8v  __attribute__((ext_vector_type(8)));   // 8 bf16 (4 VGPRs)
typedef float  f32x4 __attribute__((ext_vector_type(4)));

static __device__ __forceinline__ float sigmoidf_(float x){ return 1.f/(1.f+expf(-x)); }
static __device__ __forceinline__ short f2bf(float x){
  __hip_bfloat16 b = __float2bfloat16(x);
  return *(short*)&b;
}
static __device__ __forceinline__ float bf2f(short s){
  union { unsigned u; float f; } v; v.u = ((unsigned)(unsigned short)s) << 16; return v.f;
}
// split fp32 into hi bf16 + residual bf16 (Markidis): x ~= hi + lo
static __device__ __forceinline__ void split_bf(float x, short& hi, short& lo){
  hi = f2bf(x);
  lo = f2bf(x - bf2f(hi));
}

// ---------------- setup: counting sort of edges by (dst,type) ----------------

__global__ void count_kernel(const int* __restrict__ dst, const int* __restrict__ typ,
                             unsigned* __restrict__ deg){
  int e = blockIdx.x*256 + threadIdx.x;
  if (e < NE) atomicAdd(&deg[dst[e]*NT + typ[e]], 1u);
}

__device__ unsigned block_excl_base(unsigned threadSum){
  const int tid = threadIdx.x;
  const int lane = tid & 63, wid = tid >> 6;
  unsigned s = threadSum;
  #pragma unroll
  for (int d = 1; d < 64; d <<= 1){ unsigned t = __shfl_up(s, d); if (lane >= d) s += t; }
  __shared__ unsigned wsum[4];
  if (lane == 63) wsum[wid] = s;
  __syncthreads();
  unsigned base = 0;
  for (int w = 0; w < wid; w++) base += wsum[w];
  return base + s - threadSum;
}

__global__ void scan_reduce(const unsigned* __restrict__ deg, unsigned* __restrict__ bsum){
  const int base = blockIdx.x*1024 + threadIdx.x*4;
  unsigned s = 0;
  #pragma unroll
  for (int i = 0; i < 4; i++){ const int idx = base+i; if (idx < NBINS) s += deg[idx]; }
  #pragma unroll
  for (int d = 1; d < 64; d <<= 1) s += __shfl_down(s, d);
  __shared__ unsigned ws4[4];
  const int lane = threadIdx.x & 63, wid = threadIdx.x >> 6;
  if (lane == 0) ws4[wid] = s;
  __syncthreads();
  if (threadIdx.x == 0) bsum[blockIdx.x] = ws4[0]+ws4[1]+ws4[2]+ws4[3];
}

__global__ void scan_block(unsigned* bsum, int n){
  const int tid = threadIdx.x;
  unsigned v[4]; unsigned s = 0;
  #pragma unroll
  for (int i = 0; i < 4; i++){ const int idx = tid*4+i; v[i] = (idx < n) ? bsum[idx] : 0u; s += v[i]; }
  unsigned run = block_excl_base(s);
  #pragma unroll
  for (int i = 0; i < 4; i++){ const int idx = tid*4+i; if (idx < n) bsum[idx] = run; run += v[i]; }
}

__global__ void scan_final(const unsigned* __restrict__ deg, const unsigned* __restrict__ bsum,
                           unsigned* __restrict__ off){
  const int tid = threadIdx.x;
  const int base0 = blockIdx.x*1024 + tid*4;
  unsigned v[4]; unsigned s = 0;
  #pragma unroll
  for (int i = 0; i < 4; i++){ const int idx = base0+i; v[i] = (idx < NBINS) ? deg[idx] : 0u; s += v[i]; }
  unsigned run = block_excl_base(s) + bsum[blockIdx.x];
  #pragma unroll
  for (int i = 0; i < 4; i++){ const int idx = base0+i; if (idx < NBINS) off[idx] = run; run += v[i]; }
  if (blockIdx.x == 0 && tid == 0) off[NBINS] = NE;
}

__global__ void scatter_sort(const int* __restrict__ src, const int* __restrict__ dst,
                             const int* __restrict__ typ, unsigned* __restrict__ cur,
                             int* __restrict__ srcSorted){
  int e = blockIdx.x*256 + threadIdx.x;
  if (e < NE){
    const int bin = dst[e]*NT + typ[e];
    const unsigned p = atomicAdd(&cur[bin], 1u);
    srcSorted[p] = src[e];
  }
}

// ---------------- pack W [groups*150][150] fp32 -> bf16 hi/lo B-fragments ----------
__global__ void build_bfrag(const float* __restrict__ W, unsigned short* __restrict__ out_hi,
                            unsigned short* __restrict__ out_lo, int groups){
  const int idx = blockIdx.x*256 + threadIdx.x;
  const int total = groups*10*5*512;
  if (idx >= total) return;
  const int j = idx & 7, l = (idx>>3) & 63;
  const int fi = idx >> 9;          // (g*10+i)*5+s
  const int s = fi % 5;
  const int i = (fi/5) % 10;
  const int g = fi / 50;
  const int n = 16*i + (l & 15);
  const int k = 32*s + (l>>4)*8 + j;
  float v = 0.f;
  if (n < DD && k < DD) v = W[((size_t)(g*DD + n))*DD + k];
  short hi, lo; split_bf(v, hi, lo);
  out_hi[idx] = (unsigned short)hi;
  out_lo[idx] = (unsigned short)lo;
}

// 3-product split-precision accumulate: acc += (Ahi+Alo)*(Bhi+Blo) minus lo*lo
#define MFMA3(acc, ahi, alo, bhi, blo) \
  acc = __builtin_amdgcn_mfma_f32_16x16x32_bf16(ahi, bhi, acc, 0,0,0); \
  acc = __builtin_amdgcn_mfma_f32_16x16x32_bf16(alo, bhi, acc, 0,0,0); \
  acc = __builtin_amdgcn_mfma_f32_16x16x32_bf16(ahi, blo, acc, 0,0,0);

// accumulate one gathered h-row into the 5x8 fp32 A-fragment registers
#define GATHER_ROW(hp) \
  _Pragma("unroll") \
  for (int s = 0; s < 4; s++){ \
    const int b = 32*s + q8; \
    const float2 v0 = *(const float2*)((hp)+b),   v1 = *(const float2*)((hp)+b+2); \
    const float2 v2 = *(const float2*)((hp)+b+4), v3 = *(const float2*)((hp)+b+6); \
    a[s][0]+=v0.x; a[s][1]+=v0.y; a[s][2]+=v1.x; a[s][3]+=v1.y; \
    a[s][4]+=v2.x; a[s][5]+=v2.y; a[s][6]+=v3.x; a[s][7]+=v3.y; \
  } \
  { const int b = 128 + q8; \
    if (q < 2){ \
      const float2 v0 = *(const float2*)((hp)+b),   v1 = *(const float2*)((hp)+b+2); \
      const float2 v2 = *(const float2*)((hp)+b+4), v3 = *(const float2*)((hp)+b+6); \
      a[4][0]+=v0.x; a[4][1]+=v0.y; a[4][2]+=v1.x; a[4][3]+=v1.y; \
      a[4][4]+=v2.x; a[4][5]+=v2.y; a[4][6]+=v3.x; a[4][7]+=v3.y; \
    } else if (q == 2){ \
      const float2 v0 = *(const float2*)((hp)+b), v1 = *(const float2*)((hp)+b+2); \
      const float2 v2 = *(const float2*)((hp)+b+4); \
      a[4][0]+=v0.x; a[4][1]+=v0.y; a[4][2]+=v1.x; a[4][3]+=v1.y; \
      a[4][4]+=v2.x; a[4][5]+=v2.y; \
    } }

// ---------------- message kernel: inc = deg@b_e + sum_t agg_t @ W_t^T (MFMA) -------
// Block = 4 waves; wave handles rows [blk*64+wave*16, +16), all 150 cols.
__global__ __launch_bounds__(256, 3) void mfma_msg(
    const float* __restrict__ h, const int* __restrict__ srcS,
    const unsigned* __restrict__ off, const unsigned* __restrict__ deg,
    const float* __restrict__ b_e,
    const unsigned short* __restrict__ BfE_hi, const unsigned short* __restrict__ BfE_lo,
    float* __restrict__ inc)
{
  __shared__ float park[4][16*PKS];
  const int tid = threadIdx.x, wave = tid >> 6, l = tid & 63;
  const int m = l & 15, q = l >> 4;
  const int arow = blockIdx.x*64 + wave*16 + m;   // this lane's A-row
  const int q8 = q*8;

  f32x4 acc[10];
  #pragma unroll
  for (int i = 0; i < 10; i++) acc[i] = (f32x4)(0.0f);

  for (int t = 0; t < NT; t++){
    // gather A-fragments fp32: lane sums h[src][32s+q8+j]; 2-edge unroll for MLP
    float a[5][8];
    #pragma unroll
    for (int s = 0; s < 5; s++)
      #pragma unroll
      for (int j = 0; j < 8; j++) a[s][j] = 0.f;

    unsigned lo = 0, hi = 0;
    if (arow < NN){ const int bin = arow*NT + t; lo = off[bin]; hi = off[bin+1]; }
    unsigned e = lo;
    for (; e + 1 < hi; e += 2){
      const int s0 = srcS[e], s1 = srcS[e+1];
      const float* hp0 = h + (size_t)s0*DD;
      const float* hp1 = h + (size_t)s1*DD;
      GATHER_ROW(hp0)
      GATHER_ROW(hp1)
    }
    if (e < hi){
      const int s0 = srcS[e];
      const float* hp0 = h + (size_t)s0*DD;
      GATHER_ROW(hp0)
    }

    s8v af_hi[5], af_lo[5];
    #pragma unroll
    for (int s = 0; s < 5; s++)
      #pragma unroll
      for (int j = 0; j < 8; j++){
        short hi2, lo2; split_bf(a[s][j], hi2, lo2);
        af_hi[s][j] = hi2; af_lo[s][j] = lo2;
      }

    const unsigned short* bbh = BfE_hi + (size_t)(t*50)*512 + (size_t)l*8;
    const unsigned short* bbl = BfE_lo + (size_t)(t*50)*512 + (size_t)l*8;
    #pragma unroll
    for (int i = 0; i < 10; i++){
      #pragma unroll
      for (int s = 0; s < 5; s++){
        const s8v bh = *(const s8v*)(bbh + (i*5 + s)*512);
        const s8v bl = *(const s8v*)(bbl + (i*5 + s)*512);
        MFMA3(acc[i], af_hi[s], af_lo[s], bh, bl)
      }
    }
  }

  // park C into LDS (local row = q*4+r, col = 16i+m), then coalesced row stores
  float* pw = &park[wave][0];
  #pragma unroll
  for (int r = 0; r < 4; r++){
    const int lr = q*4 + r;
    #pragma unroll
    for (int i = 0; i < 10; i++){
      const int c = 16*i + m;
      if (c < DD) pw[lr*PKS + c] = acc[i][r];
    }
  }
  __syncthreads();

  const int rowBase = blockIdx.x*64 + wave*16;
  for (int rr = 0; rr < 16; rr++){
    const int row = rowBase + rr;
    if (row < NN){
      const uint4 dg = *(const uint4*)(&deg[row*NT]);
      const float d0=(float)dg.x, d1=(float)dg.y, d2=(float)dg.z, d3=(float)dg.w;
      float* op = inc + (size_t)row*DD;
      const int c0 = l, c1 = 64 + l, c2 = 128 + l;
      op[c0] = pw[rr*PKS + c0] + fmaf(d0, b_e[c0], fmaf(d1, b_e[DD+c0],
               fmaf(d2, b_e[2*DD+c0], d3*b_e[3*DD+c0])));
      op[c1] = pw[rr*PKS + c1] + fmaf(d0, b_e[c1], fmaf(d1, b_e[DD+c1],
               fmaf(d2, b_e[2*DD+c1], d3*b_e[3*DD+c1])));
      if (c2 < DD)
        op[c2] = pw[rr*PKS + c2] + fmaf(d0, b_e[c2], fmaf(d1, b_e[DD+c2],
                 fmaf(d2, b_e[2*DD+c2], d3*b_e[3*DD+c2])));
    }
  }
}

// ---------------- fused gi/gh GEMM + GRU: hnext = GRU(inc, hcur) --------------------
// r,z gate accumulators merged (gi+gh accumulate into one AGPR set).
__global__ __launch_bounds__(256, 3) void mfma_lingru(
    const float* __restrict__ inc, const float* __restrict__ hcur,
    const unsigned short* __restrict__ BfI_hi, const unsigned short* __restrict__ BfI_lo,
    const unsigned short* __restrict__ BfH_hi, const unsigned short* __restrict__ BfH_lo,
    const float* __restrict__ b_ih, const float* __restrict__ b_hh,
    float* __restrict__ hnext)
{
  __shared__ float park[4][16*PKS];
  const int tid = threadIdx.x, wave = tid >> 6, l = tid & 63;
  const int m = l & 15, q = l >> 4;
  const int arow = blockIdx.x*64 + wave*16 + m;
  const int q8 = q*8;
  const bool av = (arow < NN);

  // load A-fragments for inc and h rows (fp32 -> bf16 hi/lo split)
  s8v afi_h[5], afi_l[5], afh_h[5], afh_l[5];
  {
    const float* ip = inc  + (size_t)(av ? arow : 0)*DD;
    const float* hp = hcur + (size_t)(av ? arow : 0)*DD;
    #pragma unroll
    for (int s = 0; s < 5; s++){
      float ti[8] = {0,0,0,0,0,0,0,0}, th[8] = {0,0,0,0,0,0,0,0};
      const int b = 32*s + q8;
      if (av){
        if (b + 8 <= DD){
          const float2 u0=*(const float2*)(ip+b),   u1=*(const float2*)(ip+b+2);
          const float2 u2=*(const float2*)(ip+b+4), u3=*(const float2*)(ip+b+6);
          ti[0]=u0.x; ti[1]=u0.y; ti[2]=u1.x; ti[3]=u1.y; ti[4]=u2.x; ti[5]=u2.y; ti[6]=u3.x; ti[7]=u3.y;
          const float2 w0=*(const float2*)(hp+b),   w1=*(const float2*)(hp+b+2);
          const float2 w2=*(const float2*)(hp+b+4), w3=*(const float2*)(hp+b+6);
          th[0]=w0.x; th[1]=w0.y; th[2]=w1.x; th[3]=w1.y; th[4]=w2.x; th[5]=w2.y; th[6]=w3.x; th[7]=w3.y;
        } else if (b < DD){   // b==144: 6 elems
          const float2 u0=*(const float2*)(ip+b), u1=*(const float2*)(ip+b+2), u2=*(const float2*)(ip+b+4);
          ti[0]=u0.x; ti[1]=u0.y; ti[2]=u1.x; ti[3]=u1.y; ti[4]=u2.x; ti[5]=u2.y;
          const float2 w0=*(const float2*)(hp+b), w1=*(const float2*)(hp+b+2), w2=*(const float2*)(hp+b+4);
          th[0]=w0.x; th[1]=w0.y; th[2]=w1.x; th[3]=w1.y; th[4]=w2.x; th[5]=w2.y;
        }
      }
      #pragma unroll
      for (int j = 0; j < 8; j++){
        short hi2, lo2;
        split_bf(ti[j], hi2, lo2); afi_h[s][j] = hi2; afi_l[s][j] = lo2;
        split_bf(th[j], hi2, lo2); afh_h[s][j] = hi2; afh_l[s][j] = lo2;
      }
    }
  }

  const int crow0 = blockIdx.x*64 + wave*16 + q*4;
  const size_t lb = (size_t)l*8;
  float* pw = &park[wave][0];

  for (int iT = 0; iT < 10; iT++){
    f32x4 aR=(f32x4)(0.f), aZ=(f32x4)(0.f), aIN=(f32x4)(0.f), aHN=(f32x4)(0.f);
    {
      const size_t o0 = (size_t)((0*10+iT)*5)*512 + lb;
      const size_t o1 = (size_t)((1*10+iT)*5)*512 + lb;
      const size_t o2 = (size_t)((2*10+iT)*5)*512 + lb;
      #pragma unroll
      for (int s = 0; s < 5; s++){
        const size_t so = (size_t)s*512;
        const s8v bI0h=*(const s8v*)(BfI_hi+o0+so), bI0l=*(const s8v*)(BfI_lo+o0+so);
        const s8v bH0h=*(const s8v*)(BfH_hi+o0+so), bH0l=*(const s8v*)(BfH_lo+o0+so);
        MFMA3(aR, afi_h[s], afi_l[s], bI0h, bI0l)
        MFMA3(aR, afh_h[s], afh_l[s], bH0h, bH0l)
        const s8v bI1h=*(const s8v*)(BfI_hi+o1+so), bI1l=*(const s8v*)(BfI_lo+o1+so);
        const s8v bH1h=*(const s8v*)(BfH_hi+o1+so), bH1l=*(const s8v*)(BfH_lo+o1+so);
        MFMA3(aZ, afi_h[s], afi_l[s], bI1h, bI1l)
        MFMA3(aZ, afh_h[s], afh_l[s], bH1h, bH1l)
        const s8v bI2h=*(const s8v*)(BfI_hi+o2+so), bI2l=*(const s8v*)(BfI_lo+o2+so);
        const s8v bH2h=*(const s8v*)(BfH_hi+o2+so), bH2l=*(const s8v*)(BfH_lo+o2+so);
        MFMA3(aIN, afi_h[s], afi_l[s], bI2h, bI2l)
        MFMA3(aHN, afh_h[s], afh_l[s], bH2h, bH2l)
      }
    }
    const int d = 16*iT + m;
    if (d < DD){
      const float br = b_ih[d]      + b_hh[d];
      const float bz = b_ih[DD+d]   + b_hh[DD+d];
      const float bin2 = b_ih[2*DD+d];
      const float bhn  = b_hh[2*DD+d];
      #pragma unroll
      for (int r = 0; r < 4; r++){
        const int crow = crow0 + r;
        const float hv = (crow < NN) ? hcur[(size_t)crow*DD + d] : 0.f;  // L1-hot (A rows)
        const float rr = sigmoidf_(aR[r] + br);
        const float zz = sigmoidf_(aZ[r] + bz);
        const float nn = tanhf(aIN[r] + bin2 + rr*(aHN[r] + bhn));
        pw[(q*4+r)*PKS + d] = (1.f - zz)*nn + zz*hv;
      }
    }
  }

  __syncthreads();
  const int rowBase = blockIdx.x*64 + wave*16;
  for (int rr = 0; rr < 16; rr++){
    const int row = rowBase + rr;
    if (row < NN){
      float* op = hnext + (size_t)row*DD;
      op[l]      = pw[rr*PKS + l];
      op[64+l]   = pw[rr*PKS + 64 + l];
      if (l < DD-128) op[128+l] = pw[rr*PKS + 128 + l];
    }
  }
}

// ---------------- readout: two-stage segment sum, log/nan/relu, concat ----------------
__global__ void readout1(const float* __restrict__ h, const int* __restrict__ gids,
                         float* __restrict__ part){
  const int g = blockIdx.x >> 4, s = blockIdx.x & (RPB-1);
  const int tid = threadIdx.x;
  __shared__ int sb[2];
  if (tid < 2){
    const int target = g + tid;
    int lo = 0, hi = NN;
    while (lo < hi){ const int mid = (lo+hi) >> 1; if (gids[mid] < target) lo = mid+1; else hi = mid; }
    sb[tid] = lo;
  }
  __syncthreads();
  const int lo = sb[0], hi = sb[1];
  const int len = hi - lo;
  const int per = (len + RPB - 1) / RPB;
  const int nlo = lo + s*per;
  const int nhi = (nlo + per < hi) ? (nlo + per) : hi;
  if (tid < DD){
    float acc = 0.f;
    for (int n = nlo; n < nhi; n++) acc += h[(size_t)n*DD + tid];
    part[(size_t)blockIdx.x*DD + tid] = acc;
  }
}

__global__ void readout2(const float* __restrict__ part, const float* __restrict__ pclass,
                         float* __restrict__ xbuf){
  const int g = blockIdx.x, tid = threadIdx.x;
  if (tid < DD){
    float acc = 0.f;
    #pragma unroll
    for (int s = 0; s < RPB; s++) acc += part[(size_t)(g*RPB + s)*DD + tid];
    float l = logf(acc);            // log(neg)=NaN, log(0)=-inf
    if (isnan(l)) l = 0.f;          // nan -> 0
    l = fmaxf(l, 0.f);              // relu (also kills -inf)
    xbuf[g*(DD+1)+tid] = l;
  }
  if (tid == DD) xbuf[g*(DD+1)+DD] = pclass[g];
}

__global__ void fc1_kernel(const float* __restrict__ xbuf, const float* __restrict__ w,
                           const float* __restrict__ b, float* __restrict__ hid){
  const int g = blockIdx.x, tid = threadIdx.x;   // 512 threads
  __shared__ float xs[DD+1];
  if (tid < DD+1) xs[tid] = xbuf[g*(DD+1)+tid];
  __syncthreads();
  float acc = b[tid];
  for (int k = 0; k < DD+1; k++) acc = fmaf(xs[k], w[k*HIDN + tid], acc);
  hid[g*HIDN + tid] = (acc > 0.f) ? acc : 0.01f*acc;   // leaky_relu(0.01)
}

__global__ void fc2_kernel(const float* __restrict__ hid, const float* __restrict__ w,
                           const float* __restrict__ b, float* __restrict__ out){
  const int g = blockIdx.x, tid = threadIdx.x;   // 64 threads
  __shared__ float hs[HIDN];
  for (int i = tid; i < HIDN; i += 64) hs[i] = hid[g*HIDN + i];
  __syncthreads();
  if (tid < 10){
    float acc = b[tid];
    for (int k = 0; k < HIDN; k++) acc = fmaf(hs[k], w[k*10 + tid], acc);
    out[g*10 + tid] = acc;
  }
}

// ---------------- host orchestration ----------------
extern "C" void kernel_launch(void* const* d_in, const int* in_sizes, int n_in,
                              void* d_out, int out_size, void* d_ws, size_t ws_size,
                              hipStream_t stream)
{
  (void)in_sizes; (void)n_in; (void)out_size; (void)ws_size;
  const float* nodes  = (const float*)d_in[0];
  const float* pclass = (const float*)d_in[1];
  const int*   esrc   = (const int*)d_in[2];
  const int*   edst   = (const int*)d_in[3];
  const int*   etyp   = (const int*)d_in[4];
  const int*   gids   = (const int*)d_in[5];
  const float* W_e    = (const float*)d_in[6];
  const float* b_e    = (const float*)d_in[7];
  const float* w_ih   = (const float*)d_in[8];
  const float* w_hh   = (const float*)d_in[9];
  const float* b_ih   = (const float*)d_in[10];
  const float* b_hh   = (const float*)d_in[11];
  const float* fc1w   = (const float*)d_in[12];
  const float* fc1b   = (const float*)d_in[13];
  const float* fc2w   = (const float*)d_in[14];
  const float* fc2b   = (const float*)d_in[15];
  float* out = (float*)d_out;

  char* p = (char*)d_ws;
  auto alloc = [&](size_t bytes)->char* {
    char* r = p; p += ((bytes + 255) & ~(size_t)255); return r;
  };
  float*    h0   = (float*)alloc((size_t)NN*DD*4);          // 60 MB
  float*    h1   = (float*)alloc((size_t)NN*DD*4);          // 60 MB
  float*    inc  = (float*)alloc((size_t)NN*DD*4);          // 60 MB
  unsigned* deg  = (unsigned*)alloc((size_t)NBINS*4);
  unsigned* off  = (unsigned*)alloc((size_t)(NBINS+1)*4);
  unsigned* cur  = (unsigned*)alloc((size_t)NBINS*4);
  unsigned* bsum = (unsigned*)alloc(4096);
  int*      srcS = (int*)alloc((size_t)NE*4);
  unsigned short* BfEh = (unsigned short*)alloc((size_t)NT*50*512*2);
  unsigned short* BfEl = (unsigned short*)alloc((size_t)NT*50*512*2);
  unsigned short* BfIh = (unsigned short*)alloc((size_t)3*50*512*2);
  unsigned short* BfIl = (unsigned short*)alloc((size_t)3*50*512*2);
  unsigned short* BfHh = (unsigned short*)alloc((size_t)3*50*512*2);
  unsigned short* BfHl = (unsigned short*)alloc((size_t)3*50*512*2);
  float*    part = (float*)alloc((size_t)NG*RPB*DD*4);
  float*    xbuf = (float*)alloc((size_t)NG*(DD+1)*4);
  float*    hidb = (float*)alloc((size_t)NG*HIDN*4);

  // --- per-launch setup: edge CSR sort + fragment-packed weights + h init ---
  hipMemsetAsync(deg, 0, (size_t)NBINS*4, stream);
  count_kernel<<<(NE+255)/256, 256, 0, stream>>>(edst, etyp, deg);
  const int SCB = (NBINS + 1023)/1024;   // 391
  scan_reduce<<<SCB, 256, 0, stream>>>(deg, bsum);
  scan_block<<<1, 256, 0, stream>>>(bsum, SCB);
  scan_final<<<SCB, 256, 0, stream>>>(deg, bsum, off);
  hipMemcpyAsync(cur, off, (size_t)NBINS*4, hipMemcpyDeviceToDevice, stream);
  scatter_sort<<<(NE+255)/256, 256, 0, stream>>>(esrc, edst, etyp, cur, srcS);
  build_bfrag<<<(NT*50*512+255)/256, 256, 0, stream>>>(W_e,  BfEh, BfEl, NT);
  build_bfrag<<<(3*50*512+255)/256, 256, 0, stream>>>(w_ih, BfIh, BfIl, 3);
  build_bfrag<<<(3*50*512+255)/256, 256, 0, stream>>>(w_hh, BfHh, BfHl, 3);
  hipMemcpyAsync(h0, nodes, (size_t)NN*DD*4, hipMemcpyDeviceToDevice, stream);

  float* hb[2] = {h0, h1};
  const int grows = (NN + 63)/64;        // 1563
  for (int pass = 0; pass < NPASS; pass++){
    const float* hc = hb[pass & 1];
    float*       hn = hb[(pass + 1) & 1];
    mfma_msg<<<grows, 256, 0, stream>>>(hc, srcS, off, deg, b_e, BfEh, BfEl, inc);
    mfma_lingru<<<grows, 256, 0, stream>>>(inc, hc, BfIh, BfIl, BfHh, BfHl,
                                           b_ih, b_hh, hn);
  }

  readout1<<<NG*RPB, 256, 0, stream>>>(hb[NPASS & 1], gids, part);
  readout2<<<NG, 256, 0, stream>>>(part, pclass, xbuf);
  fc1_kernel<<<NG, HIDN, 0, stream>>>(xbuf, fc1w, fc1b, hidb);
  fc2_kernel<<<NG, 64, 0, stream>>>(hidb, fc2w, fc2b, out);
}

// Round 9
// 3068.275 us; speedup vs baseline: 14.5339x; 1.1851x over previous
//
#include <hip/hip_runtime.h>
#include <hip/hip_bf16.h>
#include <cstdint>
#include <cstddef>

#define NN 100000
#define NE 800000
#define NG 64
#define NT 4
#define DD 150
#define HIDN 512
#define NPASS 5
#define NBINS (NN*NT)
#define RPB 16     // readout partial blocks per graph
#define PKS 154    // park-tile row stride

typedef short  s8v  __attribute__((ext_vector_type(8)));   // 8 bf16 (4 VGPRs)
typedef float  f32x4 __attribute__((ext_vector_type(4)));

static __device__ __forceinline__ float sigmoidf_(float x){ return 1.f/(1.f+expf(-x)); }
static __device__ __forceinline__ short f2bf(float x){
  __hip_bfloat16 b = __float2bfloat16(x);
  return *(short*)&b;
}
static __device__ __forceinline__ float bf2f(short s){
  union { unsigned u; float f; } v; v.u = ((unsigned)(unsigned short)s) << 16; return v.f;
}
// split fp32 into hi bf16 + residual bf16 (Markidis): x ~= hi + lo
static __device__ __forceinline__ void split_bf(float x, short& hi, short& lo){
  hi = f2bf(x);
  lo = f2bf(x - bf2f(hi));
}

// ---------------- setup: counting sort of edges by (dst,type) ----------------

__global__ void count_kernel(const int* __restrict__ dst, const int* __restrict__ typ,
                             unsigned* __restrict__ deg){
  int e = blockIdx.x*256 + threadIdx.x;
  if (e < NE) atomicAdd(&deg[dst[e]*NT + typ[e]], 1u);
}

__device__ unsigned block_excl_base(unsigned threadSum){
  const int tid = threadIdx.x;
  const int lane = tid & 63, wid = tid >> 6;
  unsigned s = threadSum;
  #pragma unroll
  for (int d = 1; d < 64; d <<= 1){ unsigned t = __shfl_up(s, d); if (lane >= d) s += t; }
  __shared__ unsigned wsum[4];
  if (lane == 63) wsum[wid] = s;
  __syncthreads();
  unsigned base = 0;
  for (int w = 0; w < wid; w++) base += wsum[w];
  return base + s - threadSum;
}

__global__ void scan_reduce(const unsigned* __restrict__ deg, unsigned* __restrict__ bsum){
  const int base = blockIdx.x*1024 + threadIdx.x*4;
  unsigned s = 0;
  #pragma unroll
  for (int i = 0; i < 4; i++){ const int idx = base+i; if (idx < NBINS) s += deg[idx]; }
  #pragma unroll
  for (int d = 1; d < 64; d <<= 1) s += __shfl_down(s, d);
  __shared__ unsigned ws4[4];
  const int lane = threadIdx.x & 63, wid = threadIdx.x >> 6;
  if (lane == 0) ws4[wid] = s;
  __syncthreads();
  if (threadIdx.x == 0) bsum[blockIdx.x] = ws4[0]+ws4[1]+ws4[2]+ws4[3];
}

__global__ void scan_block(unsigned* bsum, int n){
  const int tid = threadIdx.x;
  unsigned v[4]; unsigned s = 0;
  #pragma unroll
  for (int i = 0; i < 4; i++){ const int idx = tid*4+i; v[i] = (idx < n) ? bsum[idx] : 0u; s += v[i]; }
  unsigned run = block_excl_base(s);
  #pragma unroll
  for (int i = 0; i < 4; i++){ const int idx = tid*4+i; if (idx < n) bsum[idx] = run; run += v[i]; }
}

__global__ void scan_final(const unsigned* __restrict__ deg, const unsigned* __restrict__ bsum,
                           unsigned* __restrict__ off){
  const int tid = threadIdx.x;
  const int base0 = blockIdx.x*1024 + tid*4;
  unsigned v[4]; unsigned s = 0;
  #pragma unroll
  for (int i = 0; i < 4; i++){ const int idx = base0+i; v[i] = (idx < NBINS) ? deg[idx] : 0u; s += v[i]; }
  unsigned run = block_excl_base(s) + bsum[blockIdx.x];
  #pragma unroll
  for (int i = 0; i < 4; i++){ const int idx = base0+i; if (idx < NBINS) off[idx] = run; run += v[i]; }
  if (blockIdx.x == 0 && tid == 0) off[NBINS] = NE;
}

__global__ void scatter_sort(const int* __restrict__ src, const int* __restrict__ dst,
                             const int* __restrict__ typ, unsigned* __restrict__ cur,
                             int* __restrict__ srcSorted){
  int e = blockIdx.x*256 + threadIdx.x;
  if (e < NE){
    const int bin = dst[e]*NT + typ[e];
    const unsigned p = atomicAdd(&cur[bin], 1u);
    srcSorted[p] = src[e];
  }
}

// ---------------- pack W [groups*150][150] fp32 -> bf16 hi/lo B-fragments ----------
__global__ void build_bfrag(const float* __restrict__ W, unsigned short* __restrict__ out_hi,
                            unsigned short* __restrict__ out_lo, int groups){
  const int idx = blockIdx.x*256 + threadIdx.x;
  const int total = groups*10*5*512;
  if (idx >= total) return;
  const int j = idx & 7, l = (idx>>3) & 63;
  const int fi = idx >> 9;          // (g*10+i)*5+s
  const int s = fi % 5;
  const int i = (fi/5) % 10;
  const int g = fi / 50;
  const int n = 16*i + (l & 15);
  const int k = 32*s + (l>>4)*8 + j;
  float v = 0.f;
  if (n < DD && k < DD) v = W[((size_t)(g*DD + n))*DD + k];
  short hi, lo; split_bf(v, hi, lo);
  out_hi[idx] = (unsigned short)hi;
  out_lo[idx] = (unsigned short)lo;
}

// 3-product split-precision accumulate: acc += (Ahi+Alo)*(Bhi+Blo) minus lo*lo
#define MFMA3(acc, ahi, alo, bhi, blo) \
  acc = __builtin_amdgcn_mfma_f32_16x16x32_bf16(ahi, bhi, acc, 0,0,0); \
  acc = __builtin_amdgcn_mfma_f32_16x16x32_bf16(alo, bhi, acc, 0,0,0); \
  acc = __builtin_amdgcn_mfma_f32_16x16x32_bf16(ahi, blo, acc, 0,0,0);

// accumulate one gathered h-row into the 5x8 fp32 A-fragment registers
#define GATHER_ROW(hp) \
  _Pragma("unroll") \
  for (int s = 0; s < 4; s++){ \
    const int b = 32*s + q8; \
    const float2 v0 = *(const float2*)((hp)+b),   v1 = *(const float2*)((hp)+b+2); \
    const float2 v2 = *(const float2*)((hp)+b+4), v3 = *(const float2*)((hp)+b+6); \
    a[s][0]+=v0.x; a[s][1]+=v0.y; a[s][2]+=v1.x; a[s][3]+=v1.y; \
    a[s][4]+=v2.x; a[s][5]+=v2.y; a[s][6]+=v3.x; a[s][7]+=v3.y; \
  } \
  { const int b = 128 + q8; \
    if (q < 2){ \
      const float2 v0 = *(const float2*)((hp)+b),   v1 = *(const float2*)((hp)+b+2); \
      const float2 v2 = *(const float2*)((hp)+b+4), v3 = *(const float2*)((hp)+b+6); \
      a[4][0]+=v0.x; a[4][1]+=v0.y; a[4][2]+=v1.x; a[4][3]+=v1.y; \
      a[4][4]+=v2.x; a[4][5]+=v2.y; a[4][6]+=v3.x; a[4][7]+=v3.y; \
    } else if (q == 2){ \
      const float2 v0 = *(const float2*)((hp)+b), v1 = *(const float2*)((hp)+b+2); \
      const float2 v2 = *(const float2*)((hp)+b+4); \
      a[4][0]+=v0.x; a[4][1]+=v0.y; a[4][2]+=v1.x; a[4][3]+=v1.y; \
      a[4][4]+=v2.x; a[4][5]+=v2.y; \
    } }

// ---------------- fused per-pass kernel: msg GEMM -> inc (LDS only) -> gi/gh GEMM -> GRU
// Block = 4 waves; wave handles rows [blk*64+wave*16, +16), all 150 cols.
__global__ __launch_bounds__(256, 3) void mfma_pass(
    const float* __restrict__ h, const int* __restrict__ srcS,
    const unsigned* __restrict__ off, const unsigned* __restrict__ deg,
    const float* __restrict__ b_e,
    const unsigned short* __restrict__ BfE_hi, const unsigned short* __restrict__ BfE_lo,
    const unsigned short* __restrict__ BfI_hi, const unsigned short* __restrict__ BfI_lo,
    const unsigned short* __restrict__ BfH_hi, const unsigned short* __restrict__ BfH_lo,
    const float* __restrict__ b_ih, const float* __restrict__ b_hh,
    float* __restrict__ hnext)
{
  __shared__ float park[4][16*PKS];
  const int tid = threadIdx.x, wave = tid >> 6, l = tid & 63;
  const int m = l & 15, q = l >> 4;
  const int arow = blockIdx.x*64 + wave*16 + m;   // this lane's A-row
  const int q8 = q*8;
  const bool av = (arow < NN);
  float* pw = &park[wave][0];

  // ======== phase 1: message GEMM: acc = sum_t agg_t @ W_t^T ========
  f32x4 acc[10];
  #pragma unroll
  for (int i = 0; i < 10; i++) acc[i] = (f32x4)(0.0f);

  for (int t = 0; t < NT; t++){
    float a[5][8];
    #pragma unroll
    for (int s = 0; s < 5; s++)
      #pragma unroll
      for (int j = 0; j < 8; j++) a[s][j] = 0.f;

    unsigned lo = 0, hi = 0;
    if (av){ const int bin = arow*NT + t; lo = off[bin]; hi = off[bin+1]; }
    unsigned e = lo;
    for (; e + 1 < hi; e += 2){
      const int s0 = srcS[e], s1 = srcS[e+1];
      const float* hp0 = h + (size_t)s0*DD;
      const float* hp1 = h + (size_t)s1*DD;
      GATHER_ROW(hp0)
      GATHER_ROW(hp1)
    }
    if (e < hi){
      const int s0 = srcS[e];
      const float* hp0 = h + (size_t)s0*DD;
      GATHER_ROW(hp0)
    }

    s8v af_hi[5], af_lo[5];
    #pragma unroll
    for (int s = 0; s < 5; s++)
      #pragma unroll
      for (int j = 0; j < 8; j++){
        short hi2, lo2; split_bf(a[s][j], hi2, lo2);
        af_hi[s][j] = hi2; af_lo[s][j] = lo2;
      }

    const unsigned short* bbh = BfE_hi + (size_t)(t*50)*512 + (size_t)l*8;
    const unsigned short* bbl = BfE_lo + (size_t)(t*50)*512 + (size_t)l*8;
    #pragma unroll
    for (int i = 0; i < 10; i++){
      #pragma unroll
      for (int s = 0; s < 5; s++){
        const s8v bh = *(const s8v*)(bbh + (i*5 + s)*512);
        const s8v bl = *(const s8v*)(bbl + (i*5 + s)*512);
        MFMA3(acc[i], af_hi[s], af_lo[s], bh, bl)
      }
    }
  }

  // ======== phase 2: add deg@b_e bias (C-layout), park inc rows ========
  const int crow0 = blockIdx.x*64 + wave*16 + q*4;
  #pragma unroll
  for (int r = 0; r < 4; r++){
    const int crow = crow0 + r;
    float d0=0.f,d1=0.f,d2=0.f,d3=0.f;
    if (crow < NN){
      const uint4 dg = *(const uint4*)(&deg[crow*NT]);
      d0=(float)dg.x; d1=(float)dg.y; d2=(float)dg.z; d3=(float)dg.w;
    }
    #pragma unroll
    for (int i = 0; i < 10; i++){
      const int c = 16*i + m;
      if (c < DD){
        const float bias = fmaf(d0, b_e[c], fmaf(d1, b_e[DD+c],
                           fmaf(d2, b_e[2*DD+c], d3*b_e[3*DD+c])));
        pw[(q*4+r)*PKS + c] = acc[i][r] + bias;
      }
    }
  }
  __syncthreads();   // park visible (wave-local in principle; barrier for safety)

  // ======== phase 3: A-fragments — inc from park (C->A transpose), hcur from global
  s8v afi_h[5], afi_l[5], afh_h[5], afh_l[5];
  {
    const float* ip = &pw[m*PKS];                       // inc row m (LDS)
    const float* hp = h + (size_t)(av ? arow : 0)*DD;   // hcur row (global)
    #pragma unroll
    for (int s = 0; s < 5; s++){
      float ti[8] = {0,0,0,0,0,0,0,0}, th[8] = {0,0,0,0,0,0,0,0};
      const int b = 32*s + q8;
      if (b + 8 <= DD){
        #pragma unroll
        for (int j = 0; j < 8; j++) ti[j] = ip[b+j];
        if (av){
          const float2 w0=*(const float2*)(hp+b),   w1=*(const float2*)(hp+b+2);
          const float2 w2=*(const float2*)(hp+b+4), w3=*(const float2*)(hp+b+6);
          th[0]=w0.x; th[1]=w0.y; th[2]=w1.x; th[3]=w1.y; th[4]=w2.x; th[5]=w2.y; th[6]=w3.x; th[7]=w3.y;
        }
      } else if (b < DD){   // b==144: 6 elems
        #pragma unroll
        for (int j = 0; j < 6; j++) ti[j] = ip[b+j];
        if (av){
          const float2 w0=*(const float2*)(hp+b), w1=*(const float2*)(hp+b+2), w2=*(const float2*)(hp+b+4);
          th[0]=w0.x; th[1]=w0.y; th[2]=w1.x; th[3]=w1.y; th[4]=w2.x; th[5]=w2.y;
        }
      }
      #pragma unroll
      for (int j = 0; j < 8; j++){
        short hi2, lo2;
        split_bf(ti[j], hi2, lo2); afi_h[s][j] = hi2; afi_l[s][j] = lo2;
        split_bf(th[j], hi2, lo2); afh_h[s][j] = hi2; afh_l[s][j] = lo2;
      }
    }
  }

  // ======== phase 4: gi/gh MFMAs + GRU, results parked (overwrite inc) ========
  const size_t lb = (size_t)l*8;
  for (int iT = 0; iT < 10; iT++){
    f32x4 aR=(f32x4)(0.f), aZ=(f32x4)(0.f), aIN=(f32x4)(0.f), aHN=(f32x4)(0.f);
    {
      const size_t o0 = (size_t)((0*10+iT)*5)*512 + lb;
      const size_t o1 = (size_t)((1*10+iT)*5)*512 + lb;
      const size_t o2 = (size_t)((2*10+iT)*5)*512 + lb;
      #pragma unroll
      for (int s = 0; s < 5; s++){
        const size_t so = (size_t)s*512;
        const s8v bI0h=*(const s8v*)(BfI_hi+o0+so), bI0l=*(const s8v*)(BfI_lo+o0+so);
        const s8v bH0h=*(const s8v*)(BfH_hi+o0+so), bH0l=*(const s8v*)(BfH_lo+o0+so);
        MFMA3(aR, afi_h[s], afi_l[s], bI0h, bI0l)
        MFMA3(aR, afh_h[s], afh_l[s], bH0h, bH0l)
        const s8v bI1h=*(const s8v*)(BfI_hi+o1+so), bI1l=*(const s8v*)(BfI_lo+o1+so);
        const s8v bH1h=*(const s8v*)(BfH_hi+o1+so), bH1l=*(const s8v*)(BfH_lo+o1+so);
        MFMA3(aZ, afi_h[s], afi_l[s], bI1h, bI1l)
        MFMA3(aZ, afh_h[s], afh_l[s], bH1h, bH1l)
        const s8v bI2h=*(const s8v*)(BfI_hi+o2+so), bI2l=*(const s8v*)(BfI_lo+o2+so);
        const s8v bH2h=*(const s8v*)(BfH_hi+o2+so), bH2l=*(const s8v*)(BfH_lo+o2+so);
        MFMA3(aIN, afi_h[s], afi_l[s], bI2h, bI2l)
        MFMA3(aHN, afh_h[s], afh_l[s], bH2h, bH2l)
      }
    }
    const int d = 16*iT + m;
    if (d < DD){
      const float br   = b_ih[d]    + b_hh[d];
      const float bz   = b_ih[DD+d] + b_hh[DD+d];
      const float bin2 = b_ih[2*DD+d];
      const float bhn  = b_hh[2*DD+d];
      #pragma unroll
      for (int r = 0; r < 4; r++){
        const int crow = crow0 + r;
        const float hv = (crow < NN) ? h[(size_t)crow*DD + d] : 0.f;
        const float rr = sigmoidf_(aR[r] + br);
        const float zz = sigmoidf_(aZ[r] + bz);
        const float nn = tanhf(aIN[r] + bin2 + rr*(aHN[r] + bhn));
        pw[(q*4+r)*PKS + d] = (1.f - zz)*nn + zz*hv;
      }
    }
  }

  // ======== phase 5: coalesced hnext row stores ========
  __syncthreads();
  const int rowBase = blockIdx.x*64 + wave*16;
  for (int rr = 0; rr < 16; rr++){
    const int row = rowBase + rr;
    if (row < NN){
      float* op = hnext + (size_t)row*DD;
      op[l]      = pw[rr*PKS + l];
      op[64+l]   = pw[rr*PKS + 64 + l];
      if (l < DD-128) op[128+l] = pw[rr*PKS + 128 + l];
    }
  }
}

// ---------------- readout: two-stage segment sum, log/nan/relu, concat ----------------
__global__ void readout1(const float* __restrict__ h, const int* __restrict__ gids,
                         float* __restrict__ part){
  const int g = blockIdx.x >> 4, s = blockIdx.x & (RPB-1);
  const int tid = threadIdx.x;
  __shared__ int sb[2];
  if (tid < 2){
    const int target = g + tid;
    int lo = 0, hi = NN;
    while (lo < hi){ const int mid = (lo+hi) >> 1; if (gids[mid] < target) lo = mid+1; else hi = mid; }
    sb[tid] = lo;
  }
  __syncthreads();
  const int lo = sb[0], hi = sb[1];
  const int len = hi - lo;
  const int per = (len + RPB - 1) / RPB;
  const int nlo = lo + s*per;
  const int nhi = (nlo + per < hi) ? (nlo + per) : hi;
  if (tid < DD){
    float acc = 0.f;
    for (int n = nlo; n < nhi; n++) acc += h[(size_t)n*DD + tid];
    part[(size_t)blockIdx.x*DD + tid] = acc;
  }
}

__global__ void readout2(const float* __restrict__ part, const float* __restrict__ pclass,
                         float* __restrict__ xbuf){
  const int g = blockIdx.x, tid = threadIdx.x;
  if (tid < DD){
    float acc = 0.f;
    #pragma unroll
    for (int s = 0; s < RPB; s++) acc += part[(size_t)(g*RPB + s)*DD + tid];
    float l = logf(acc);            // log(neg)=NaN, log(0)=-inf
    if (isnan(l)) l = 0.f;          // nan -> 0
    l = fmaxf(l, 0.f);              // relu (also kills -inf)
    xbuf[g*(DD+1)+tid] = l;
  }
  if (tid == DD) xbuf[g*(DD+1)+DD] = pclass[g];
}

__global__ void fc1_kernel(const float* __restrict__ xbuf, const float* __restrict__ w,
                           const float* __restrict__ b, float* __restrict__ hid){
  const int g = blockIdx.x, tid = threadIdx.x;   // 512 threads
  __shared__ float xs[DD+1];
  if (tid < DD+1) xs[tid] = xbuf[g*(DD+1)+tid];
  __syncthreads();
  float acc = b[tid];
  for (int k = 0; k < DD+1; k++) acc = fmaf(xs[k], w[k*HIDN + tid], acc);
  hid[g*HIDN + tid] = (acc > 0.f) ? acc : 0.01f*acc;   // leaky_relu(0.01)
}

__global__ void fc2_kernel(const float* __restrict__ hid, const float* __restrict__ w,
                           const float* __restrict__ b, float* __restrict__ out){
  const int g = blockIdx.x, tid = threadIdx.x;   // 64 threads
  __shared__ float hs[HIDN];
  for (int i = tid; i < HIDN; i += 64) hs[i] = hid[g*HIDN + i];
  __syncthreads();
  if (tid < 10){
    float acc = b[tid];
    for (int k = 0; k < HIDN; k++) acc = fmaf(hs[k], w[k*10 + tid], acc);
    out[g*10 + tid] = acc;
  }
}

// ---------------- host orchestration ----------------
extern "C" void kernel_launch(void* const* d_in, const int* in_sizes, int n_in,
                              void* d_out, int out_size, void* d_ws, size_t ws_size,
                              hipStream_t stream)
{
  (void)in_sizes; (void)n_in; (void)out_size; (void)ws_size;
  const float* nodes  = (const float*)d_in[0];
  const float* pclass = (const float*)d_in[1];
  const int*   esrc   = (const int*)d_in[2];
  const int*   edst   = (const int*)d_in[3];
  const int*   etyp   = (const int*)d_in[4];
  const int*   gids   = (const int*)d_in[5];
  const float* W_e    = (const float*)d_in[6];
  const float* b_e    = (const float*)d_in[7];
  const float* w_ih   = (const float*)d_in[8];
  const float* w_hh   = (const float*)d_in[9];
  const float* b_ih   = (const float*)d_in[10];
  const float* b_hh   = (const float*)d_in[11];
  const float* fc1w   = (const float*)d_in[12];
  const float* fc1b   = (const float*)d_in[13];
  const float* fc2w   = (const float*)d_in[14];
  const float* fc2b   = (const float*)d_in[15];
  float* out = (float*)d_out;

  char* p = (char*)d_ws;
  auto alloc = [&](size_t bytes)->char* {
    char* r = p; p += ((bytes + 255) & ~(size_t)255); return r;
  };
  float*    h0   = (float*)alloc((size_t)NN*DD*4);          // 60 MB
  float*    h1   = (float*)alloc((size_t)NN*DD*4);          // 60 MB
  unsigned* deg  = (unsigned*)alloc((size_t)NBINS*4);
  unsigned* off  = (unsigned*)alloc((size_t)(NBINS+1)*4);
  unsigned* cur  = (unsigned*)alloc((size_t)NBINS*4);
  unsigned* bsum = (unsigned*)alloc(4096);
  int*      srcS = (int*)alloc((size_t)NE*4);
  unsigned short* BfEh = (unsigned short*)alloc((size_t)NT*50*512*2);
  unsigned short* BfEl = (unsigned short*)alloc((size_t)NT*50*512*2);
  unsigned short* BfIh = (unsigned short*)alloc((size_t)3*50*512*2);
  unsigned short* BfIl = (unsigned short*)alloc((size_t)3*50*512*2);
  unsigned short* BfHh = (unsigned short*)alloc((size_t)3*50*512*2);
  unsigned short* BfHl = (unsigned short*)alloc((size_t)3*50*512*2);
  float*    part = (float*)alloc((size_t)NG*RPB*DD*4);
  float*    xbuf = (float*)alloc((size_t)NG*(DD+1)*4);
  float*    hidb = (float*)alloc((size_t)NG*HIDN*4);

  // --- per-launch setup: edge CSR sort + fragment-packed weights + h init ---
  hipMemsetAsync(deg, 0, (size_t)NBINS*4, stream);
  count_kernel<<<(NE+255)/256, 256, 0, stream>>>(edst, etyp, deg);
  const int SCB = (NBINS + 1023)/1024;   // 391
  scan_reduce<<<SCB, 256, 0, stream>>>(deg, bsum);
  scan_block<<<1, 256, 0, stream>>>(bsum, SCB);
  scan_final<<<SCB, 256, 0, stream>>>(deg, bsum, off);
  hipMemcpyAsync(cur, off, (size_t)NBINS*4, hipMemcpyDeviceToDevice, stream);
  scatter_sort<<<(NE+255)/256, 256, 0, stream>>>(esrc, edst, etyp, cur, srcS);
  build_bfrag<<<(NT*50*512+255)/256, 256, 0, stream>>>(W_e,  BfEh, BfEl, NT);
  build_bfrag<<<(3*50*512+255)/256, 256, 0, stream>>>(w_ih, BfIh, BfIl, 3);
  build_bfrag<<<(3*50*512+255)/256, 256, 0, stream>>>(w_hh, BfHh, BfHl, 3);
  hipMemcpyAsync(h0, nodes, (size_t)NN*DD*4, hipMemcpyDeviceToDevice, stream);

  float* hb[2] = {h0, h1};
  const int grows = (NN + 63)/64;        // 1563
  for (int pass = 0; pass < NPASS; pass++){
    const float* hc = hb[pass & 1];
    float*       hn = hb[(pass + 1) & 1];
    mfma_pass<<<grows, 256, 0, stream>>>(hc, srcS, off, deg, b_e, BfEh, BfEl,
                                         BfIh, BfIl, BfHh, BfHl, b_ih, b_hh, hn);
  }

  readout1<<<NG*RPB, 256, 0, stream>>>(hb[NPASS & 1], gids, part);
  readout2<<<NG, 256, 0, stream>>>(part, pclass, xbuf);
  fc1_kernel<<<NG, HIDN, 0, stream>>>(xbuf, fc1w, fc1b, hidb);
  fc2_kernel<<<NG, 64, 0, stream>>>(hidb, fc2w, fc2b, out);
}